// Round 6
// baseline (864.205 us; speedup 1.0000x reference)
//
#include <hip/hip_runtime.h>

// Problem constants: B=32 graphs, N=1024 nodes/graph, F=64, D=128, DEG=8
#define E_TOTAL 262144     // B*N*DEG
#define NGRAPH  32
#define EPG     8192       // edges per graph
#define EPS_BN  1e-5f
#define MB (1u << 20)
#define KB (1u << 10)

__device__ __forceinline__ float lrelu(float x){ return x > 0.f ? x : 0.2f * x; }

// ---- per-graph gate primitives (r3 lesson: no single-line RMW storms, no full-grid
// arrival spikes; 32 counters 64B apart, arrivals spread in time). Agent scope keeps
// cross-XCD visibility correct regardless of the (undefined) block->XCD mapping. ----
__device__ __forceinline__ void gate_ge(const int* c, int tgt){
  if (threadIdx.x == 0)
    while (__hip_atomic_load(c, __ATOMIC_RELAXED, __HIP_MEMORY_SCOPE_AGENT) < tgt)
      __builtin_amdgcn_s_sleep(2);
  __syncthreads();
  (void)__hip_atomic_load(c, __ATOMIC_ACQUIRE, __HIP_MEMORY_SCOPE_AGENT);
}
__device__ __forceinline__ void rel_inc(int* c){
  __syncthreads();   // all block stores drained (vmcnt0) before t0 publishes
  if (threadIdx.x == 0)
    (void)__hip_atomic_fetch_add(c, 1, __ATOMIC_RELEASE, __HIP_MEMORY_SCOPE_AGENT);
}

// exclusive scan of B = 256*Q LDS bins by 256 threads; writes cnt/row_start globals,
// leaves per-bin exclusive cursors in h. Caller must barrier before entry.
template<int Q>
__device__ __forceinline__ void scan_bins(int* h, int* cnt_g, int* rs_g, int B, int g,
                                          int ebase, int* wsum){
  int t = threadIdx.x, lane = t & 63, w = t >> 6;
  int c[Q]; int s = 0;
  #pragma unroll
  for (int i = 0; i < Q; ++i){ c[i] = h[t * Q + i]; s += c[i]; }
  int v = s;
  #pragma unroll
  for (int o = 1; o < 64; o <<= 1){ int u = __shfl_up(v, o); if (lane >= o) v += u; }
  if (lane == 63) wsum[w] = v;
  __syncthreads();
  if (t == 0){ int run = 0;
    #pragma unroll
    for (int i = 0; i < 4; ++i){ int x = wsum[i]; wsum[i] = run; run += x; } }
  __syncthreads();
  int run = v - s + wsum[w];
  #pragma unroll
  for (int i = 0; i < Q; ++i){
    cnt_g[g * B + t * Q + i] = c[i];
    rs_g [g * B + t * Q + i] = ebase + run;
    h[t * Q + i] = run;
    run += c[i];
  }
  __syncthreads();
}

// ---------------- device bodies ----------------------------------------------------------

// layer-1 GEMM tile (K=64, no BN): h = x0 @ W0 for 32 rows + es/ed epilogue
__device__ __forceinline__ void gemm1_tile(const float* __restrict__ x0,
    const float* __restrict__ W0, const float* __restrict__ a_s,
    const float* __restrict__ a_d, float* __restrict__ C, float* __restrict__ es,
    float* __restrict__ ed, int tile, float* Ws, float* As_t){
  int t = threadIdx.x;
  int row0 = tile * 32;
  int c2 = t & 63, rg = t >> 6;
  float2 acc[8];
  #pragma unroll
  for (int i = 0; i < 8; ++i){ acc[i].x = 0.f; acc[i].y = 0.f; }
  for (int i = t; i < 8192; i += 256) Ws[i] = W0[i];
  #pragma unroll
  for (int it = 0; it < 8; ++it){
    int i = it * 256 + t;
    int r = i >> 6, kk = i & 63;
    As_t[kk * 36 + r] = x0[(size_t)(row0 + r) * 64 + kk];
  }
  __syncthreads();
  #pragma unroll 8
  for (int kk = 0; kk < 64; ++kk){
    float2 w = *(float2*)&Ws[kk * 128 + c2 * 2];
    float4 a0 = *(float4*)&As_t[kk * 36 + rg * 8];
    float4 a1 = *(float4*)&As_t[kk * 36 + rg * 8 + 4];
    acc[0].x = fmaf(a0.x, w.x, acc[0].x); acc[0].y = fmaf(a0.x, w.y, acc[0].y);
    acc[1].x = fmaf(a0.y, w.x, acc[1].x); acc[1].y = fmaf(a0.y, w.y, acc[1].y);
    acc[2].x = fmaf(a0.z, w.x, acc[2].x); acc[2].y = fmaf(a0.z, w.y, acc[2].y);
    acc[3].x = fmaf(a0.w, w.x, acc[3].x); acc[3].y = fmaf(a0.w, w.y, acc[3].y);
    acc[4].x = fmaf(a1.x, w.x, acc[4].x); acc[4].y = fmaf(a1.x, w.y, acc[4].y);
    acc[5].x = fmaf(a1.y, w.x, acc[5].x); acc[5].y = fmaf(a1.y, w.y, acc[5].y);
    acc[6].x = fmaf(a1.z, w.x, acc[6].x); acc[6].y = fmaf(a1.z, w.y, acc[6].y);
    acc[7].x = fmaf(a1.w, w.x, acc[7].x); acc[7].y = fmaf(a1.w, w.y, acc[7].y);
  }
  float2 as2 = ((const float2*)a_s)[c2];
  float2 ad2 = ((const float2*)a_d)[c2];
  float2* C2 = (float2*)C;
  #pragma unroll
  for (int i = 0; i < 8; ++i){
    int r = row0 + rg * 8 + i;
    C2[(size_t)r * 64 + c2] = acc[i];
    float e1 = acc[i].x * as2.x + acc[i].y * as2.y;
    float e2 = acc[i].x * ad2.x + acc[i].y * ad2.y;
    #pragma unroll
    for (int o = 32; o; o >>= 1){ e1 += __shfl_xor(e1, o); e2 += __shfl_xor(e2, o); }
    if (c2 == 0){ es[r] = e1; ed[r] = e2; }
  }
}

// K=128 GEMM tile with BN applied from LDS mu/rsig
__device__ __forceinline__ void gemm128_tile(const float* __restrict__ A,
    const float* __restrict__ W, const float* __restrict__ a_s,
    const float* __restrict__ a_d, float* __restrict__ C, float* __restrict__ es,
    float* __restrict__ ed, int tile, float* Ws, float* As_t,
    const float* bnmu, const float* bnrs){
  int t = threadIdx.x;
  int row0 = tile * 32;
  int c2 = t & 63, rg = t >> 6;
  float2 acc[8];
  #pragma unroll
  for (int i = 0; i < 8; ++i){ acc[i].x = 0.f; acc[i].y = 0.f; }
  for (int k0 = 0; k0 < 128; k0 += 64){
    __syncthreads();
    for (int i = t; i < 8192; i += 256)
      Ws[i] = W[(size_t)(k0 + (i >> 7)) * 128 + (i & 127)];
    #pragma unroll
    for (int it = 0; it < 8; ++it){
      int i = it * 256 + t;
      int r = i >> 6, kk = i & 63;
      float v = A[(size_t)(row0 + r) * 128 + k0 + kk];
      v = (v - bnmu[k0 + kk]) * bnrs[k0 + kk];
      As_t[kk * 36 + r] = v;
    }
    __syncthreads();
    #pragma unroll 8
    for (int kk = 0; kk < 64; ++kk){
      float2 w = *(float2*)&Ws[kk * 128 + c2 * 2];
      float4 a0 = *(float4*)&As_t[kk * 36 + rg * 8];
      float4 a1 = *(float4*)&As_t[kk * 36 + rg * 8 + 4];
      acc[0].x = fmaf(a0.x, w.x, acc[0].x); acc[0].y = fmaf(a0.x, w.y, acc[0].y);
      acc[1].x = fmaf(a0.y, w.x, acc[1].x); acc[1].y = fmaf(a0.y, w.y, acc[1].y);
      acc[2].x = fmaf(a0.z, w.x, acc[2].x); acc[2].y = fmaf(a0.z, w.y, acc[2].y);
      acc[3].x = fmaf(a0.w, w.x, acc[3].x); acc[3].y = fmaf(a0.w, w.y, acc[3].y);
      acc[4].x = fmaf(a1.x, w.x, acc[4].x); acc[4].y = fmaf(a1.x, w.y, acc[4].y);
      acc[5].x = fmaf(a1.y, w.x, acc[5].x); acc[5].y = fmaf(a1.y, w.y, acc[5].y);
      acc[6].x = fmaf(a1.z, w.x, acc[6].x); acc[6].y = fmaf(a1.z, w.y, acc[6].y);
      acc[7].x = fmaf(a1.w, w.x, acc[7].x); acc[7].y = fmaf(a1.w, w.y, acc[7].y);
    }
  }
  float2 as2 = ((const float2*)a_s)[c2];
  float2 ad2 = ((const float2*)a_d)[c2];
  float2* C2 = (float2*)C;
  #pragma unroll
  for (int i = 0; i < 8; ++i){
    int r = row0 + rg * 8 + i;
    C2[(size_t)r * 64 + c2] = acc[i];
    float e1 = acc[i].x * as2.x + acc[i].y * as2.y;
    float e2 = acc[i].x * ad2.x + acc[i].y * ad2.y;
    #pragma unroll
    for (int o = 32; o; o >>= 1){ e1 += __shfl_xor(e1, o); e2 += __shfl_xor(e2, o); }
    if (c2 == 0){ es[r] = e1; ed[r] = e2; }
  }
}

// GAT softmax-aggregate + bias + ReLU + pairwise max-pool for 4 nodes (1/wave),
// + banked BN partial accumulation. osh = 4*64 float2 LDS scratch.
__device__ __forceinline__ void gat_group(const float* __restrict__ h,
    const float* __restrict__ es, const float* __restrict__ ed,
    const int* __restrict__ csr_src, const int* __restrict__ row_start,
    const int* __restrict__ row_cnt, const float* __restrict__ bias,
    float* __restrict__ xout, float* __restrict__ partials, int group, float2* osh){
  int lane = threadIdx.x & 63;
  int wave = threadIdx.x >> 6;
  int n = group * 4 + wave;
  int start = row_start[n];
  int cnt   = row_cnt[n];
  float edn = ed[n];
  float selfl = lrelu(es[n] + edn);

  float m_l = -1e30f, d_l = 0.f;
  int   s_c = 0; float l_c = 0.f;
  for (int c0 = 0; c0 < cnt; c0 += 64){
    int j = c0 + lane;
    if (j < cnt){
      int s = csr_src[start + j];
      float l = lrelu(es[s] + edn);
      if (c0 == 0){ s_c = s; l_c = l; }
      float mn = fmaxf(m_l, l);
      d_l = d_l * __expf(m_l - mn) + __expf(l - mn);
      m_l = mn;
    }
  }
  #pragma unroll
  for (int o = 32; o; o >>= 1){
    float m2 = __shfl_xor(m_l, o), d2 = __shfl_xor(d_l, o);
    float mn = fmaxf(m_l, m2);
    d_l = d_l * __expf(m_l - mn) + d2 * __expf(m2 - mn);
    m_l = mn;
  }
  float mf  = fmaxf(m_l, selfl);
  float den = d_l * __expf(m_l - mf) + __expf(selfl - mf);

  const float2* h2 = (const float2*)h;
  float sw = __expf(selfl - mf);
  float2 hv = h2[(size_t)n * 64 + lane];
  float2 acc; acc.x = sw * hv.x; acc.y = sw * hv.y;
  for (int c0 = 0; c0 < cnt; c0 += 64){
    int j = c0 + lane;
    int s_j; float w_j;
    if (c0 == 0){
      s_j = s_c;
      w_j = (lane < cnt) ? __expf(l_c - mf) : 0.f;
    } else {
      s_j = 0; w_j = 0.f;
      if (j < cnt){
        s_j = csr_src[start + j];
        w_j = __expf(lrelu(es[s_j] + edn) - mf);
      }
    }
    int rem = min(64, cnt - c0);
    int k = 0;
    for (; k + 8 <= rem; k += 8){
      int ss[8]; float ww[8]; float2 hh[8];
      #pragma unroll
      for (int i = 0; i < 8; ++i){ ss[i] = __shfl(s_j, k + i); ww[i] = __shfl(w_j, k + i); }
      #pragma unroll
      for (int i = 0; i < 8; ++i){ hh[i] = h2[(size_t)ss[i] * 64 + lane]; }
      #pragma unroll
      for (int i = 0; i < 8; ++i){
        acc.x = fmaf(ww[i], hh[i].x, acc.x);
        acc.y = fmaf(ww[i], hh[i].y, acc.y);
      }
    }
    for (; k < rem; ++k){
      int s = __shfl(s_j, k); float w = __shfl(w_j, k);
      float2 hh = h2[(size_t)s * 64 + lane];
      acc.x = fmaf(w, hh.x, acc.x);
      acc.y = fmaf(w, hh.y, acc.y);
    }
  }
  float inv = 1.f / den;
  float2 bv = ((const float2*)bias)[lane];
  float2 o2;
  o2.x = fmaxf(acc.x * inv + bv.x, 0.f);
  o2.y = fmaxf(acc.y * inv + bv.y, 0.f);
  osh[wave * 64 + lane] = o2;
  __syncthreads();
  float2 p;
  if (wave < 2){
    float2 a = osh[2 * wave * 64 + lane], b = osh[(2 * wave + 1) * 64 + lane];
    p.x = fmaxf(a.x, b.x); p.y = fmaxf(a.y, b.y);
    ((float2*)xout)[(size_t)(group * 2 + wave) * 64 + lane] = p;
  }
  __syncthreads();
  if (wave < 2) osh[wave * 64 + lane] = p;
  __syncthreads();
  float* part = partials + ((group & 63) << 8);
  if (wave == 0){
    float2 a = osh[lane], b = osh[64 + lane];
    atomicAdd(&part[2 * lane],     a.x + b.x);
    atomicAdd(&part[2 * lane + 1], a.y + b.y);
  } else if (wave == 1){
    float2 a = osh[lane], b = osh[64 + lane];
    atomicAdd(&part[128 + 2 * lane],     a.x * a.x + b.x * b.x);
    atomicAdd(&part[128 + 2 * lane + 1], a.y * a.y + b.y * b.y);
  }
  __syncthreads();
}

// ---------------- K1: persistent fused CSR(all layers) + gemm1 + gat1 --------------------
// 512 blocks, all guaranteed co-resident (__launch_bounds__(256,2); LDS 45KB -> 3/CU).
// Static item list per block: items b, b+512, ... ascending:
//   [0,96):    CSR roles (role=item>>5, graph=item&31); role0 releases cc[g]
//   [96,1120): gemm1 tiles; release gc1[tile>>5] (32 tiles/graph)
//   [1120,9312): gat1 groups of 4 nodes; gate gc1[g]==32 && cc[g]==1
// Deadlock-free by construction: every block's csr/gemm items precede its gat items and
// all items are statically owned by co-resident blocks.
__global__ __launch_bounds__(256, 2)
void k1(const float* __restrict__ x0, const float* __restrict__ W0,
        const float* __restrict__ a_s, const float* __restrict__ a_d,
        const int* __restrict__ src0, const int* __restrict__ dst0,
        float* __restrict__ C, float* __restrict__ es, float* __restrict__ ed,
        int* __restrict__ csr1, int* __restrict__ csr2, int* __restrict__ csr3,
        int* __restrict__ rs1, int* __restrict__ rs2, int* __restrict__ rs3,
        int* __restrict__ cnt1, int* __restrict__ cnt2, int* __restrict__ cnt3,
        const float* __restrict__ bias, float* __restrict__ xout,
        float* __restrict__ partials0, int* __restrict__ cc, int* __restrict__ gc1){
  __shared__ __align__(16) char smem[45056];
  __shared__ int wsum[4];
  int t = threadIdx.x;

  for (int item = blockIdx.x; item < 9312; item += 512){
    __syncthreads();
    if (item < 96){
      int* bm2 = (int*)smem;
      int* bm3 = bm2 + 8192;
      int* h   = bm3 + 2048;
      int role = item >> 5, g = item & 31, ebase = g * EPG;
      if (role == 0){
        for (int i = t; i < 1024; i += 256) h[i] = 0;
        __syncthreads();
        for (int i = 0; i < 32; ++i){
          int e = ebase + i * 256 + t;
          int sv = src0[e], dv = dst0[e];
          if (sv != dv) atomicAdd(&h[dv & 1023], 1);
        }
        __syncthreads();
        scan_bins<4>(h, cnt1, rs1, 1024, g, ebase, wsum);
        for (int i = 0; i < 32; ++i){
          int e = ebase + i * 256 + t;
          int sv = src0[e], dv = dst0[e];
          if (sv != dv){
            int p = atomicAdd(&h[dv & 1023], 1);
            csr1[ebase + p] = sv;
          }
        }
        rel_inc(&cc[g * 16]);
      } else if (role == 1){
        for (int i = t; i < 8192; i += 256) bm2[i] = 0;
        for (int i = t; i < 512; i += 256) h[i] = 0;
        __syncthreads();
        unsigned int k2m = 0;
        for (int i = 0; i < 32; ++i){
          int e = ebase + i * 256 + t;
          int sv = src0[e], dv = dst0[e];
          if (sv != dv){
            int s2 = (sv >> 1) & 511, d2 = (dv >> 1) & 511;
            if (s2 != d2){
              int key = (s2 << 9) | d2;
              unsigned int bit = 1u << (key & 31);
              unsigned int old = atomicOr((unsigned int*)&bm2[key >> 5], bit);
              if (!(old & bit)){ k2m |= 1u << i; atomicAdd(&h[d2], 1); }
            }
          }
        }
        __syncthreads();
        scan_bins<2>(h, cnt2, rs2, 512, g, ebase, wsum);
        for (int i = 0; i < 32; ++i){
          if ((k2m >> i) & 1u){
            int e = ebase + i * 256 + t;
            int sv = src0[e], dv = dst0[e];
            int p = atomicAdd(&h[(dv >> 1) & 511], 1);
            csr2[ebase + p] = sv >> 1;
          }
        }
      } else {
        for (int i = t; i < 8192; i += 256) bm2[i] = 0;
        for (int i = t; i < 2048; i += 256) bm3[i] = 0;
        for (int i = t; i < 256; i += 256) h[i] = 0;
        __syncthreads();
        unsigned int k3m = 0;
        for (int i = 0; i < 32; ++i){
          int e = ebase + i * 256 + t;
          int sv = src0[e], dv = dst0[e];
          if (sv != dv){
            int s2 = (sv >> 1) & 511, d2 = (dv >> 1) & 511;
            if (s2 != d2){
              int key = (s2 << 9) | d2;
              unsigned int bit = 1u << (key & 31);
              unsigned int old = atomicOr((unsigned int*)&bm2[key >> 5], bit);
              if (!(old & bit)){
                int s3 = (sv >> 2) & 255, d3 = (dv >> 2) & 255;
                if (s3 != d3){
                  int key3 = (s3 << 8) | d3;
                  unsigned int b3 = 1u << (key3 & 31);
                  unsigned int o3 = atomicOr((unsigned int*)&bm3[key3 >> 5], b3);
                  if (!(o3 & b3)){ k3m |= 1u << i; atomicAdd(&h[d3], 1); }
                }
              }
            }
          }
        }
        __syncthreads();
        scan_bins<1>(h, cnt3, rs3, 256, g, ebase, wsum);
        for (int i = 0; i < 32; ++i){
          if ((k3m >> i) & 1u){
            int e = ebase + i * 256 + t;
            int sv = src0[e], dv = dst0[e];
            int p = atomicAdd(&h[(dv >> 2) & 255], 1);
            csr3[ebase + p] = sv >> 2;
          }
        }
      }
    } else if (item < 1120){
      int tile = item - 96;
      float* Ws   = (float*)smem;
      float* As_t = Ws + 8192;
      gemm1_tile(x0, W0, a_s, a_d, C, es, ed, tile, Ws, As_t);
      rel_inc(&gc1[(tile >> 5) * 16]);
    } else {
      int group = item - 1120;
      int g = group >> 8;
      gate_ge(&gc1[g * 16], 32);
      gate_ge(&cc[g * 16], 1);
      gat_group(C, es, ed, csr1, rs1, cnt1, bias, xout, partials0, group, (float2*)smem);
    }
  }
}

// ---------------- K2/K3: persistent fused {BN-from-partials + gemm128 + gat} ------------
__global__ __launch_bounds__(256, 2)
void k23(const float* __restrict__ A, const float* __restrict__ W,
         const float* __restrict__ partials_in, float invM,
         const float* __restrict__ a_s, const float* __restrict__ a_d,
         float* __restrict__ C, float* __restrict__ es, float* __restrict__ ed,
         const int* __restrict__ csr, const int* __restrict__ rs,
         const int* __restrict__ cnt_, const float* __restrict__ bias,
         float* __restrict__ xout, float* __restrict__ partials_out,
         int* __restrict__ gc, int n_gemm, int n_gat, int tpg_sh, int gpg_sh){
  __shared__ float Ws[8192];        // 32 KB (gat reuses head as osh scratch)
  __shared__ float As_t[64 * 36];   // 9 KB
  __shared__ float red[256];
  __shared__ float bnmu[128], bnrs[128];
  int t = threadIdx.x;
  {
    float s = 0.f;
    #pragma unroll
    for (int k = 0; k < 64; ++k) s += partials_in[(k << 8) + t];
    red[t] = s;
  }
  __syncthreads();
  if (t < 128){
    float mu = red[t] * invM;
    float var = red[128 + t] * invM - mu * mu;
    bnmu[t] = mu; bnrs[t] = rsqrtf(var + EPS_BN);
  }
  __syncthreads();
  int target = n_gemm >> 5;     // tiles per graph (L2: 16, L3: 8)
  int total = n_gemm + n_gat;
  for (int item = blockIdx.x; item < total; item += 512){
    __syncthreads();
    if (item < n_gemm){
      gemm128_tile(A, W, a_s, a_d, C, es, ed, item, Ws, As_t, bnmu, bnrs);
      rel_inc(&gc[(item >> tpg_sh) * 16]);
    } else {
      int group = item - n_gemm;
      gate_ge(&gc[(group >> gpg_sh) * 16], target);
      gat_group(C, es, ed, csr, rs, cnt_, bias, xout, partials_out, group, (float2*)Ws);
    }
  }
}

// ---------------- final BatchNorm: reduce partials + normalize ---------------------------
__global__ __launch_bounds__(256)
void bn_norm(const float* __restrict__ in, const float* __restrict__ partials,
             float* __restrict__ out, int M){
  __shared__ float red[256];
  __shared__ float mu_s[128], rs_s[128];
  int t = threadIdx.x;
  {
    float s = 0.f;
    #pragma unroll
    for (int k = 0; k < 64; ++k) s += partials[(k << 8) + t];
    red[t] = s;
  }
  __syncthreads();
  if (t < 128){
    float mu = red[t] / (float)M;
    float var = red[128 + t] / (float)M - mu * mu;
    mu_s[t] = mu; rs_s[t] = rsqrtf(var + EPS_BN);
  }
  __syncthreads();
  int total = M * 128;
  for (int idx = blockIdx.x * 256 + t; idx < total; idx += gridDim.x * 256){
    int c = idx & 127;
    out[idx] = (in[idx] - mu_s[c]) * rs_s[c];
  }
}

extern "C" void kernel_launch(void* const* d_in, const int* in_sizes, int n_in,
                              void* d_out, int out_size, void* d_ws, size_t ws_size,
                              hipStream_t stream){
  const float* x0   = (const float*)d_in[0];
  const float* W0   = (const float*)d_in[1];
  const float* W1   = (const float*)d_in[2];
  const float* W2   = (const float*)d_in[3];
  const float* attS = (const float*)d_in[4];
  const float* attD = (const float*)d_in[5];
  const float* bias = (const float*)d_in[6];
  const int*   src0 = (const int*)d_in[7];
  const int*   dst0 = src0 + E_TOTAL;
  float* out = (float*)d_out;                  // (32, 16384) f32

  char* ws = (char*)d_ws;
  float* Hbuf   = (float*)(ws);                        // 16 MB
  float* Xa     = (float*)(ws + 16 * MB);              //  8 MB (pooled ping)
  int*   csr1   = (int*)  (ws + 24 * MB);              //  1 MB
  int*   csr2   = (int*)  (ws + 25 * MB);              //  1 MB
  int*   csr3   = (int*)  (ws + 26 * MB);              //  1 MB
  float* es     = (float*)(ws + 27 * MB);              // 128 KB
  float* ed     = (float*)(ws + 27 * MB + 128 * KB);   // 128 KB
  int*   rs1    = (int*)  (ws + 27 * MB + 256 * KB);   // 128 KB
  int*   rs2    = (int*)  (ws + 27 * MB + 384 * KB);   //  64 KB
  int*   rs3    = (int*)  (ws + 27 * MB + 448 * KB);   //  32 KB
  int*   cnt1   = (int*)  (ws + 27 * MB + 480 * KB);   // 128 KB
  int*   cnt2   = (int*)  (ws + 27 * MB + 608 * KB);   //  64 KB
  int*   cnt3   = (int*)  (ws + 27 * MB + 672 * KB);   //  32 KB
  float* parts  = (float*)(ws + 27 * MB + 704 * KB);   // 3 x 64 x 256 floats (192 KB)
  int*   cc     = (int*)  (ws + 27 * MB + 896 * KB);   // 4 arrays x 32 cntrs x 64B
  int*   gc1    = cc + 512;
  int*   gc2    = gc1 + 512;
  int*   gc3    = gc2 + 512;
  float* Xb     = (float*)(ws + 28 * MB);              //  4 MB (pooled pong)
  float* parts0 = parts, *parts1 = parts + 64 * 256, *parts2 = parts + 2 * 64 * 256;

  // zero BN partials + gate counters (192 KB + 8 KB)
  hipMemsetAsync(parts, 0, 192 * KB + 8 * KB, stream);

  // ---- K1: CSR(all layers) + gemm1 + gat1 -> Xa ----
  k1<<<512, 256, 0, stream>>>(x0, W0, attS, attD, src0, dst0, Hbuf, es, ed,
                              csr1, csr2, csr3, rs1, rs2, rs3, cnt1, cnt2, cnt3,
                              bias, Xa, parts0, cc, gc1);

  // ---- K2: layer 2 fused (512 gemm tiles, tpg_sh=4; 4096 gat groups, gpg_sh=7) ----
  k23<<<512, 256, 0, stream>>>(Xa, W1, parts0, 1.f / 16384.f, attS + 128, attD + 128,
                               Hbuf, es, ed, csr2, rs2, cnt2, bias + 128, Xb, parts1,
                               gc2, 512, 4096, 4, 7);

  // ---- K3: layer 3 fused (256 gemm tiles, tpg_sh=3; 2048 gat groups, gpg_sh=6) ----
  k23<<<512, 256, 0, stream>>>(Xb, W2, parts1, 1.f / 8192.f, attS + 256, attD + 256,
                               Hbuf, es, ed, csr3, rs3, cnt3, bias + 256, Xa, parts2,
                               gc3, 256, 2048, 3, 6);

  // ---- final BN over Xa (4096 rows) ----
  bn_norm<<<512, 256, 0, stream>>>(Xa, parts2, out, 4096);
}

// Round 7
// 216.783 us; speedup vs baseline: 3.9865x; 3.9865x over previous
//
#include <hip/hip_runtime.h>

// Problem constants: B=32 graphs, N=1024 nodes/graph, F=64, D=128, DEG=8
#define E_TOTAL 262144     // B*N*DEG
#define NGRAPH  32
#define EPG     8192       // edges per graph
#define EPS_BN  1e-5f
#define MB (1u << 20)
#define KB (1u << 10)

// LESSON (r3/r6, twice-measured): in-kernel cross-block sync on MI355X costs 45-500 us
// (agent-scope release/acquire => per-XCD L2 writeback/invalidate storms). The kernel
// launch boundary (~10 us) is the cheapest device-wide sync. NO in-kernel gates/barriers.

__device__ __forceinline__ float lrelu(float x){ return x > 0.f ? x : 0.2f * x; }

// XCD-aware block swizzle (locality-neutral measured, harmless).
__device__ __forceinline__ int xcd_swz(int b, int n){ return (b & 7) * (n >> 3) + (b >> 3); }

// exclusive scan of B = 256*Q LDS bins by 256 threads; writes cnt/row_start globals,
// leaves per-bin exclusive cursors in h. Caller must barrier before entry.
template<int Q>
__device__ __forceinline__ void scan_bins(int* h, int* cnt_g, int* rs_g, int B, int g,
                                          int ebase, int* wsum){
  int t = threadIdx.x, lane = t & 63, w = t >> 6;
  int c[Q]; int s = 0;
  #pragma unroll
  for (int i = 0; i < Q; ++i){ c[i] = h[t * Q + i]; s += c[i]; }
  int v = s;
  #pragma unroll
  for (int o = 1; o < 64; o <<= 1){ int u = __shfl_up(v, o); if (lane >= o) v += u; }
  if (lane == 63) wsum[w] = v;
  __syncthreads();
  if (t == 0){ int run = 0;
    #pragma unroll
    for (int i = 0; i < 4; ++i){ int x = wsum[i]; wsum[i] = run; run += x; } }
  __syncthreads();
  int run = v - s + wsum[w];
  #pragma unroll
  for (int i = 0; i < Q; ++i){
    cnt_g[g * B + t * Q + i] = c[i];
    rs_g [g * B + t * Q + i] = ebase + run;
    h[t * Q + i] = run;
    run += c[i];
  }
  __syncthreads();
}

// ---------------- mega1: CSR build (all 3 layers) CO-DISPATCHED with layer-1 GEMM -------
// blocks 0..95: CSR. role 0 (0-31): L1 hist+scan+scatter (no dedupe) + zero the 3 layers'
// BN partial arrays. role 1: L2 pair-dedupe. role 2: L2-redo + L3 dedupe. 256 thr,
// 32 edges/thread. blocks 96..1119: layer-1 GEMM (1024 tiles of 32 rows) + es/ed.
__global__ __launch_bounds__(256, 2)
void mega1(const float* __restrict__ x0, const float* __restrict__ W0,
           const float* __restrict__ a_s, const float* __restrict__ a_d,
           const int* __restrict__ src0, const int* __restrict__ dst0,
           float* __restrict__ C, float* __restrict__ es, float* __restrict__ ed,
           int* __restrict__ csr1, int* __restrict__ csr2, int* __restrict__ csr3,
           int* __restrict__ rs1, int* __restrict__ rs2, int* __restrict__ rs3,
           int* __restrict__ cnt1, int* __restrict__ cnt2, int* __restrict__ cnt3,
           float* __restrict__ partials_all){
  __shared__ __align__(16) char smem[45072];   // union: csr 44KB / gemm 41KB
  __shared__ int wsum[4];
  int t = threadIdx.x;
  int raw = blockIdx.x;

  if (raw < 96){
    int* bm2 = (int*)smem;          // [8192] 32 KB
    int* bm3 = bm2 + 8192;          // [2048]  8 KB
    int* h   = bm3 + 2048;          // [1024]  4 KB
    int role = raw >> 5, g = raw & 31, ebase = g * EPG;

    if (role == 0){
      // zero 3 layers x 64 banks x 256 BN partials (49152 floats) across 32 blocks
      for (int i = g * 256 + t; i < 3 * 64 * 256; i += 8192) partials_all[i] = 0.f;
      // ---- L1: no dedupe, 1024 bins ----
      for (int i = t; i < 1024; i += 256) h[i] = 0;
      __syncthreads();
      for (int i = 0; i < 32; ++i){
        int e = ebase + i * 256 + t;
        int sv = src0[e], dv = dst0[e];
        if (sv != dv) atomicAdd(&h[dv & 1023], 1);
      }
      __syncthreads();
      scan_bins<4>(h, cnt1, rs1, 1024, g, ebase, wsum);
      for (int i = 0; i < 32; ++i){
        int e = ebase + i * 256 + t;
        int sv = src0[e], dv = dst0[e];
        if (sv != dv){
          int p = atomicAdd(&h[dv & 1023], 1);
          csr1[ebase + p] = sv;
        }
      }
    } else if (role == 1){
      // ---- L2: pair-dedupe (512x512 bitmap), 512 bins ----
      for (int i = t; i < 8192; i += 256) bm2[i] = 0;
      for (int i = t; i < 512; i += 256) h[i] = 0;
      __syncthreads();
      unsigned int k2m = 0;
      for (int i = 0; i < 32; ++i){
        int e = ebase + i * 256 + t;
        int sv = src0[e], dv = dst0[e];
        if (sv != dv){
          int s2 = (sv >> 1) & 511, d2 = (dv >> 1) & 511;
          if (s2 != d2){
            int key = (s2 << 9) | d2;
            unsigned int bit = 1u << (key & 31);
            unsigned int old = atomicOr((unsigned int*)&bm2[key >> 5], bit);
            if (!(old & bit)){ k2m |= 1u << i; atomicAdd(&h[d2], 1); }
          }
        }
      }
      __syncthreads();
      scan_bins<2>(h, cnt2, rs2, 512, g, ebase, wsum);
      for (int i = 0; i < 32; ++i){
        if ((k2m >> i) & 1u){
          int e = ebase + i * 256 + t;
          int sv = src0[e], dv = dst0[e];
          int p = atomicAdd(&h[(dv >> 1) & 511], 1);
          csr2[ebase + p] = sv >> 1;
        }
      }
    } else {
      // ---- L3: redo L2 dedupe (independent bitmap) then L3 dedupe, 256 bins ----
      for (int i = t; i < 8192; i += 256) bm2[i] = 0;
      for (int i = t; i < 2048; i += 256) bm3[i] = 0;
      for (int i = t; i < 256; i += 256) h[i] = 0;
      __syncthreads();
      unsigned int k3m = 0;
      for (int i = 0; i < 32; ++i){
        int e = ebase + i * 256 + t;
        int sv = src0[e], dv = dst0[e];
        if (sv != dv){
          int s2 = (sv >> 1) & 511, d2 = (dv >> 1) & 511;
          if (s2 != d2){
            int key = (s2 << 9) | d2;
            unsigned int bit = 1u << (key & 31);
            unsigned int old = atomicOr((unsigned int*)&bm2[key >> 5], bit);
            if (!(old & bit)){
              int s3 = (sv >> 2) & 255, d3 = (dv >> 2) & 255;
              if (s3 != d3){
                int key3 = (s3 << 8) | d3;
                unsigned int b3 = 1u << (key3 & 31);
                unsigned int o3 = atomicOr((unsigned int*)&bm3[key3 >> 5], b3);
                if (!(o3 & b3)){ k3m |= 1u << i; atomicAdd(&h[d3], 1); }
              }
            }
          }
        }
      }
      __syncthreads();
      scan_bins<1>(h, cnt3, rs3, 256, g, ebase, wsum);
      for (int i = 0; i < 32; ++i){
        if ((k3m >> i) & 1u){
          int e = ebase + i * 256 + t;
          int sv = src0[e], dv = dst0[e];
          int p = atomicAdd(&h[(dv >> 2) & 255], 1);
          csr3[ebase + p] = sv >> 2;
        }
      }
    }
    return;
  }

  // ---- layer-1 GEMM tile (K=64, no BN) ----
  float* Ws   = (float*)smem;       // [64*128] 32 KB
  float* As_t = Ws + 8192;          // [64*36]   9 KB
  int tile = xcd_swz(raw - 96, 1024);
  int row0 = tile * 32;
  int c2 = t & 63, rg = t >> 6;
  float2 acc[8];
  #pragma unroll
  for (int i = 0; i < 8; ++i){ acc[i].x = 0.f; acc[i].y = 0.f; }

  for (int i = t; i < 8192; i += 256) Ws[i] = W0[i];
  #pragma unroll
  for (int it = 0; it < 8; ++it){
    int i = it * 256 + t;
    int r = i >> 6, kk = i & 63;
    As_t[kk * 36 + r] = x0[(size_t)(row0 + r) * 64 + kk];
  }
  __syncthreads();
  #pragma unroll 8
  for (int kk = 0; kk < 64; ++kk){
    float2 w = *(float2*)&Ws[kk * 128 + c2 * 2];
    float4 a0 = *(float4*)&As_t[kk * 36 + rg * 8];
    float4 a1 = *(float4*)&As_t[kk * 36 + rg * 8 + 4];
    acc[0].x = fmaf(a0.x, w.x, acc[0].x); acc[0].y = fmaf(a0.x, w.y, acc[0].y);
    acc[1].x = fmaf(a0.y, w.x, acc[1].x); acc[1].y = fmaf(a0.y, w.y, acc[1].y);
    acc[2].x = fmaf(a0.z, w.x, acc[2].x); acc[2].y = fmaf(a0.z, w.y, acc[2].y);
    acc[3].x = fmaf(a0.w, w.x, acc[3].x); acc[3].y = fmaf(a0.w, w.y, acc[3].y);
    acc[4].x = fmaf(a1.x, w.x, acc[4].x); acc[4].y = fmaf(a1.x, w.y, acc[4].y);
    acc[5].x = fmaf(a1.y, w.x, acc[5].x); acc[5].y = fmaf(a1.y, w.y, acc[5].y);
    acc[6].x = fmaf(a1.z, w.x, acc[6].x); acc[6].y = fmaf(a1.z, w.y, acc[6].y);
    acc[7].x = fmaf(a1.w, w.x, acc[7].x); acc[7].y = fmaf(a1.w, w.y, acc[7].y);
  }
  float2 as2 = ((const float2*)a_s)[c2];
  float2 ad2 = ((const float2*)a_d)[c2];
  float2* C2 = (float2*)C;
  #pragma unroll
  for (int i = 0; i < 8; ++i){
    int r = row0 + rg * 8 + i;
    C2[(size_t)r * 64 + c2] = acc[i];
    float e1 = acc[i].x * as2.x + acc[i].y * as2.y;
    float e2 = acc[i].x * ad2.x + acc[i].y * ad2.y;
    #pragma unroll
    for (int o = 32; o; o >>= 1){ e1 += __shfl_xor(e1, o); e2 += __shfl_xor(e2, o); }
    if (c2 == 0){ es[r] = e1; ed[r] = e2; }
  }
}

// ---------------- GEMM (K=128) + attention terms; BN stats from 64-bank partials --------
// Prologue reduces partials[64][256] (written by the preceding gat_pool) into mu/rsig.
// The producer->consumer kernel-launch boundary is the only synchronization needed.
__global__ __launch_bounds__(256)
void gemm_attn128(const float* __restrict__ A, const float* __restrict__ W,
                  const float* __restrict__ partials, float invM,
                  const float* __restrict__ a_s, const float* __restrict__ a_d,
                  float* __restrict__ C, float* __restrict__ es, float* __restrict__ ed){
  __shared__ float Ws[64 * 128];    // 32 KB
  __shared__ float As_t[64 * 36];   // 9 KB
  __shared__ float red[256];
  __shared__ float bnmu[128], bnrs[128];
  int t = threadIdx.x;
  {
    float s = 0.f;
    #pragma unroll
    for (int k = 0; k < 64; ++k) s += partials[(k << 8) + t];
    red[t] = s;
  }
  __syncthreads();
  if (t < 128){
    float mu = red[t] * invM;
    float var = red[128 + t] * invM - mu * mu;
    bnmu[t] = mu; bnrs[t] = rsqrtf(var + EPS_BN);
  }
  int bid = xcd_swz(blockIdx.x, gridDim.x);
  int row0 = bid * 32;
  int c2 = t & 63, rg = t >> 6;
  float2 acc[8];
  #pragma unroll
  for (int i = 0; i < 8; ++i){ acc[i].x = 0.f; acc[i].y = 0.f; }

  for (int k0 = 0; k0 < 128; k0 += 64){
    __syncthreads();
    for (int i = t; i < 64 * 128; i += 256)
      Ws[i] = W[(size_t)(k0 + (i >> 7)) * 128 + (i & 127)];
    #pragma unroll
    for (int it = 0; it < 8; ++it){
      int i = it * 256 + t;
      int r = i >> 6, kk = i & 63;
      float v = A[(size_t)(row0 + r) * 128 + k0 + kk];
      v = (v - bnmu[k0 + kk]) * bnrs[k0 + kk];
      As_t[kk * 36 + r] = v;
    }
    __syncthreads();
    #pragma unroll 8
    for (int kk = 0; kk < 64; ++kk){
      float2 w = *(float2*)&Ws[kk * 128 + c2 * 2];
      float4 a0 = *(float4*)&As_t[kk * 36 + rg * 8];
      float4 a1 = *(float4*)&As_t[kk * 36 + rg * 8 + 4];
      acc[0].x = fmaf(a0.x, w.x, acc[0].x); acc[0].y = fmaf(a0.x, w.y, acc[0].y);
      acc[1].x = fmaf(a0.y, w.x, acc[1].x); acc[1].y = fmaf(a0.y, w.y, acc[1].y);
      acc[2].x = fmaf(a0.z, w.x, acc[2].x); acc[2].y = fmaf(a0.z, w.y, acc[2].y);
      acc[3].x = fmaf(a0.w, w.x, acc[3].x); acc[3].y = fmaf(a0.w, w.y, acc[3].y);
      acc[4].x = fmaf(a1.x, w.x, acc[4].x); acc[4].y = fmaf(a1.x, w.y, acc[4].y);
      acc[5].x = fmaf(a1.y, w.x, acc[5].x); acc[5].y = fmaf(a1.y, w.y, acc[5].y);
      acc[6].x = fmaf(a1.z, w.x, acc[6].x); acc[6].y = fmaf(a1.z, w.y, acc[6].y);
      acc[7].x = fmaf(a1.w, w.x, acc[7].x); acc[7].y = fmaf(a1.w, w.y, acc[7].y);
    }
  }
  float2 as2 = ((const float2*)a_s)[c2];
  float2 ad2 = ((const float2*)a_d)[c2];
  float2* C2 = (float2*)C;
  #pragma unroll
  for (int i = 0; i < 8; ++i){
    int r = row0 + rg * 8 + i;
    C2[(size_t)r * 64 + c2] = acc[i];
    float e1 = acc[i].x * as2.x + acc[i].y * as2.y;
    float e2 = acc[i].x * ad2.x + acc[i].y * ad2.y;
    #pragma unroll
    for (int o = 32; o; o >>= 1){ e1 += __shfl_xor(e1, o); e2 += __shfl_xor(e2, o); }
    if (c2 == 0){ es[r] = e1; ed[r] = e2; }
  }
}

// ---------------- GAT softmax-aggregate + bias + ReLU + pairwise max-pool ----------------
// 16 nodes per block (4 groups of 4, one group per wave per iteration) -> 4x fewer
// workgroups than r5 (cuts CP dispatch ramp) + BN partials batched in registers across
// the 4 iterations (one atomic per lane at the end instead of 4).
__global__ void gat_pool(const float* __restrict__ h, const float* __restrict__ es,
                         const float* __restrict__ ed, const int* __restrict__ csr_src,
                         const int* __restrict__ row_start, const int* __restrict__ row_cnt,
                         const float* __restrict__ bias, float* __restrict__ xout,
                         float* __restrict__ partials, int M){
  __shared__ float2 osh[4][64];
  int lane = threadIdx.x & 63;
  int wave = threadIdx.x >> 6;
  int bid = xcd_swz(blockIdx.x, gridDim.x);
  const float2* h2 = (const float2*)h;
  float2 bv = ((const float2*)bias)[lane];
  float2 racc; racc.x = 0.f; racc.y = 0.f;   // wave0: sum, wave1: sumsq

  for (int it = 0; it < 4; ++it){
    int group = bid * 4 + it;
    int n = group * 4 + wave;
    int start = row_start[n];
    int cnt   = row_cnt[n];
    float edn = ed[n];
    float selfl = lrelu(es[n] + edn);

    // phase A: online softmax stats, lane-parallel; cache first chunk in regs
    float m_l = -1e30f, d_l = 0.f;
    int   s_c = 0; float l_c = 0.f;
    for (int c0 = 0; c0 < cnt; c0 += 64){
      int j = c0 + lane;
      if (j < cnt){
        int s = csr_src[start + j];
        float l = lrelu(es[s] + edn);
        if (c0 == 0){ s_c = s; l_c = l; }
        float mn = fmaxf(m_l, l);
        d_l = d_l * __expf(m_l - mn) + __expf(l - mn);
        m_l = mn;
      }
    }
    #pragma unroll
    for (int o = 32; o; o >>= 1){
      float m2 = __shfl_xor(m_l, o), d2 = __shfl_xor(d_l, o);
      float mn = fmaxf(m_l, m2);
      d_l = d_l * __expf(m_l - mn) + d2 * __expf(m2 - mn);
      m_l = mn;
    }
    float mf  = fmaxf(m_l, selfl);
    float den = d_l * __expf(m_l - mf) + __expf(selfl - mf);

    // phase B: weighted accumulation, 8 gathers in flight via shfl-broadcast indices
    float sw = __expf(selfl - mf);
    float2 hv = h2[(size_t)n * 64 + lane];
    float2 acc; acc.x = sw * hv.x; acc.y = sw * hv.y;
    for (int c0 = 0; c0 < cnt; c0 += 64){
      int j = c0 + lane;
      int s_j; float w_j;
      if (c0 == 0){
        s_j = s_c;
        w_j = (lane < cnt) ? __expf(l_c - mf) : 0.f;
      } else {
        s_j = 0; w_j = 0.f;
        if (j < cnt){
          s_j = csr_src[start + j];
          w_j = __expf(lrelu(es[s_j] + edn) - mf);
        }
      }
      int rem = min(64, cnt - c0);
      int k = 0;
      for (; k + 8 <= rem; k += 8){
        int ss[8]; float ww[8]; float2 hh[8];
        #pragma unroll
        for (int i = 0; i < 8; ++i){ ss[i] = __shfl(s_j, k + i); ww[i] = __shfl(w_j, k + i); }
        #pragma unroll
        for (int i = 0; i < 8; ++i){ hh[i] = h2[(size_t)ss[i] * 64 + lane]; }
        #pragma unroll
        for (int i = 0; i < 8; ++i){
          acc.x = fmaf(ww[i], hh[i].x, acc.x);
          acc.y = fmaf(ww[i], hh[i].y, acc.y);
        }
      }
      for (; k < rem; ++k){
        int s = __shfl(s_j, k); float w = __shfl(w_j, k);
        float2 hh = h2[(size_t)s * 64 + lane];
        acc.x = fmaf(w, hh.x, acc.x);
        acc.y = fmaf(w, hh.y, acc.y);
      }
    }
    float inv = 1.f / den;
    float2 o2;
    o2.x = fmaxf(acc.x * inv + bv.x, 0.f);
    o2.y = fmaxf(acc.y * inv + bv.y, 0.f);
    osh[wave][lane] = o2;
    __syncthreads();
    float2 p;
    if (wave < 2){
      float2 a = osh[2 * wave][lane], b = osh[2 * wave + 1][lane];
      p.x = fmaxf(a.x, b.x); p.y = fmaxf(a.y, b.y);
      ((float2*)xout)[(size_t)(group * 2 + wave) * 64 + lane] = p;
    }
    __syncthreads();
    if (wave < 2) osh[wave][lane] = p;   // pooled rows 0,1 of this iteration
    __syncthreads();
    if (wave == 0){
      float2 a = osh[0][lane], b = osh[1][lane];
      racc.x += a.x + b.x;
      racc.y += a.y + b.y;
    } else if (wave == 1){
      float2 a = osh[0][lane], b = osh[1][lane];
      racc.x += a.x * a.x + b.x * b.x;
      racc.y += a.y * a.y + b.y * b.y;
    }
    __syncthreads();
  }
  float* part = partials + ((bid & 63) << 8);
  if (wave == 0){
    atomicAdd(&part[2 * lane],     racc.x);
    atomicAdd(&part[2 * lane + 1], racc.y);
  } else if (wave == 1){
    atomicAdd(&part[128 + 2 * lane],     racc.x);
    atomicAdd(&part[128 + 2 * lane + 1], racc.y);
  }
}

// ---------------- final BatchNorm: reduce partials + normalize, one kernel ---------------
__global__ __launch_bounds__(256)
void bn_norm(const float* __restrict__ in, const float* __restrict__ partials,
             float* __restrict__ out, int M){
  __shared__ float red[256];
  __shared__ float mu_s[128], rs_s[128];
  int t = threadIdx.x;
  {
    float s = 0.f;
    #pragma unroll
    for (int k = 0; k < 64; ++k) s += partials[(k << 8) + t];
    red[t] = s;
  }
  __syncthreads();
  if (t < 128){
    float mu = red[t] / (float)M;
    float var = red[128 + t] / (float)M - mu * mu;
    mu_s[t] = mu; rs_s[t] = rsqrtf(var + EPS_BN);
  }
  __syncthreads();
  int total = M * 128;
  for (int idx = blockIdx.x * 256 + t; idx < total; idx += gridDim.x * 256){
    int c = idx & 127;
    out[idx] = (in[idx] - mu_s[c]) * rs_s[c];
  }
}

extern "C" void kernel_launch(void* const* d_in, const int* in_sizes, int n_in,
                              void* d_out, int out_size, void* d_ws, size_t ws_size,
                              hipStream_t stream){
  const float* x0   = (const float*)d_in[0];
  const float* W0   = (const float*)d_in[1];
  const float* W1   = (const float*)d_in[2];
  const float* W2   = (const float*)d_in[3];
  const float* attS = (const float*)d_in[4];
  const float* attD = (const float*)d_in[5];
  const float* bias = (const float*)d_in[6];
  const int*   src0 = (const int*)d_in[7];
  const int*   dst0 = src0 + E_TOTAL;
  float* out = (float*)d_out;                  // (32, 16384) f32

  char* ws = (char*)d_ws;
  float* Hbuf   = (float*)(ws);                        // 16 MB
  float* Xbuf   = (float*)(ws + 16 * MB);              //  8 MB (pooled)
  int*   csr1   = (int*)  (ws + 24 * MB);              //  1 MB
  int*   csr2   = (int*)  (ws + 25 * MB);              //  1 MB
  int*   csr3   = (int*)  (ws + 26 * MB);              //  1 MB
  float* es     = (float*)(ws + 27 * MB);              // 128 KB
  float* ed     = (float*)(ws + 27 * MB + 128 * KB);   // 128 KB
  int*   rs1    = (int*)  (ws + 27 * MB + 256 * KB);   // 128 KB
  int*   rs2    = (int*)  (ws + 27 * MB + 384 * KB);   //  64 KB
  int*   rs3    = (int*)  (ws + 27 * MB + 448 * KB);   //  32 KB
  int*   cnt1   = (int*)  (ws + 27 * MB + 480 * KB);   // 128 KB
  int*   cnt2   = (int*)  (ws + 27 * MB + 608 * KB);   //  64 KB
  int*   cnt3   = (int*)  (ws + 27 * MB + 672 * KB);   //  32 KB
  float* parts  = (float*)(ws + 27 * MB + 704 * KB);   // 3 x 64 x 256 floats (192 KB)
  float* parts0 = parts, *parts1 = parts + 64 * 256, *parts2 = parts + 2 * 64 * 256;

  // ---- CSR (all 3 layers) co-dispatched with layer-1 GEMM; zeroes BN partials ----
  mega1<<<1120, 256, 0, stream>>>(x0, W0, attS, attD, src0, dst0, Hbuf, es, ed,
                                  csr1, csr2, csr3, rs1, rs2, rs3, cnt1, cnt2, cnt3,
                                  parts);

  // ---- layer 1 aggregate (16 nodes/block) ----
  gat_pool<<<2048, 256, 0, stream>>>(Hbuf, es, ed, csr1, rs1, cnt1, bias, Xbuf,
                                     parts0, 32768);

  // ---- layer 2 ----
  gemm_attn128<<<512, 256, 0, stream>>>(Xbuf, W1, parts0, 1.f / 16384.f,
                                        attS + 128, attD + 128, Hbuf, es, ed);
  gat_pool<<<1024, 256, 0, stream>>>(Hbuf, es, ed, csr2, rs2, cnt2, bias + 128, Xbuf,
                                     parts1, 16384);

  // ---- layer 3 ----
  gemm_attn128<<<256, 256, 0, stream>>>(Xbuf, W2, parts1, 1.f / 8192.f,
                                        attS + 256, attD + 256, Hbuf, es, ed);
  gat_pool<<<512, 256, 0, stream>>>(Hbuf, es, ed, csr3, rs3, cnt3, bias + 256, Xbuf,
                                    parts2, 8192);

  // ---- final BN: reduce partials + normalize ----
  bn_norm<<<512, 256, 0, stream>>>(Xbuf, parts2, out, 4096);
}

// Round 8
// 207.786 us; speedup vs baseline: 4.1591x; 1.0433x over previous
//
#include <hip/hip_runtime.h>

// Problem constants: B=32 graphs, N=1024 nodes/graph, F=64, D=128, DEG=8
#define E_TOTAL 262144     // B*N*DEG
#define NGRAPH  32
#define EPG     8192       // edges per graph
#define EPS_BN  1e-5f
#define MB (1u << 20)
#define KB (1u << 10)

// LESSON (r3/r6, twice-measured): in-kernel cross-block sync on MI355X costs 45-500 us
// (agent-scope release/acquire => per-XCD L2 writeback/invalidate storms). Launch
// boundaries (~10 us) are the sync primitive. NO in-kernel gates/barriers.
// LESSON (r7): gat_pool wants max independent waves; batching rows per block couples
// variable-degree rows via __syncthreads and regresses. Keep 4 nodes/block.

__device__ __forceinline__ float lrelu(float x){ return x > 0.f ? x : 0.2f * x; }

// XCD-aware block swizzle (locality-neutral measured, harmless).
__device__ __forceinline__ int xcd_swz(int b, int n){ return (b & 7) * (n >> 3) + (b >> 3); }

// exclusive scan of B = 256*Q LDS bins by 256 threads; writes cnt/row_start globals,
// leaves per-bin exclusive cursors in h. Caller must barrier before entry.
template<int Q>
__device__ __forceinline__ void scan_bins(int* h, int* cnt_g, int* rs_g, int B, int g,
                                          int ebase, int* wsum){
  int t = threadIdx.x, lane = t & 63, w = t >> 6;
  int c[Q]; int s = 0;
  #pragma unroll
  for (int i = 0; i < Q; ++i){ c[i] = h[t * Q + i]; s += c[i]; }
  int v = s;
  #pragma unroll
  for (int o = 1; o < 64; o <<= 1){ int u = __shfl_up(v, o); if (lane >= o) v += u; }
  if (lane == 63) wsum[w] = v;
  __syncthreads();
  if (t == 0){ int run = 0;
    #pragma unroll
    for (int i = 0; i < 4; ++i){ int x = wsum[i]; wsum[i] = run; run += x; } }
  __syncthreads();
  int run = v - s + wsum[w];
  #pragma unroll
  for (int i = 0; i < Q; ++i){
    cnt_g[g * B + t * Q + i] = c[i];
    rs_g [g * B + t * Q + i] = ebase + run;
    h[t * Q + i] = run;
    run += c[i];
  }
  __syncthreads();
}

// GAT softmax-aggregate + bias + ReLU + pairwise max-pool for one group of 4 nodes
// (one node per wave) + banked BN partial accumulation. osh = 4*64 float2 LDS scratch.
__device__ __forceinline__ void gat_group(const float* __restrict__ h,
    const float* __restrict__ es, const float* __restrict__ ed,
    const int* __restrict__ csr_src, const int* __restrict__ row_start,
    const int* __restrict__ row_cnt, const float* __restrict__ bias,
    float* __restrict__ xout, float* __restrict__ partials, int group, float2* osh){
  int lane = threadIdx.x & 63;
  int wave = threadIdx.x >> 6;
  int n = group * 4 + wave;
  int start = row_start[n];
  int cnt   = row_cnt[n];
  float edn = ed[n];
  float selfl = lrelu(es[n] + edn);

  // phase A: online softmax stats, lane-parallel; cache first chunk in regs
  float m_l = -1e30f, d_l = 0.f;
  int   s_c = 0; float l_c = 0.f;
  for (int c0 = 0; c0 < cnt; c0 += 64){
    int j = c0 + lane;
    if (j < cnt){
      int s = csr_src[start + j];
      float l = lrelu(es[s] + edn);
      if (c0 == 0){ s_c = s; l_c = l; }
      float mn = fmaxf(m_l, l);
      d_l = d_l * __expf(m_l - mn) + __expf(l - mn);
      m_l = mn;
    }
  }
  #pragma unroll
  for (int o = 32; o; o >>= 1){
    float m2 = __shfl_xor(m_l, o), d2 = __shfl_xor(d_l, o);
    float mn = fmaxf(m_l, m2);
    d_l = d_l * __expf(m_l - mn) + d2 * __expf(m2 - mn);
    m_l = mn;
  }
  float mf  = fmaxf(m_l, selfl);
  float den = d_l * __expf(m_l - mf) + __expf(selfl - mf);

  // phase B: weighted accumulation, 8 gathers in flight via shfl-broadcast indices
  const float2* h2 = (const float2*)h;
  float sw = __expf(selfl - mf);
  float2 hv = h2[(size_t)n * 64 + lane];
  float2 acc; acc.x = sw * hv.x; acc.y = sw * hv.y;
  for (int c0 = 0; c0 < cnt; c0 += 64){
    int j = c0 + lane;
    int s_j; float w_j;
    if (c0 == 0){
      s_j = s_c;
      w_j = (lane < cnt) ? __expf(l_c - mf) : 0.f;
    } else {
      s_j = 0; w_j = 0.f;
      if (j < cnt){
        s_j = csr_src[start + j];
        w_j = __expf(lrelu(es[s_j] + edn) - mf);
      }
    }
    int rem = min(64, cnt - c0);
    int k = 0;
    for (; k + 8 <= rem; k += 8){
      int ss[8]; float ww[8]; float2 hh[8];
      #pragma unroll
      for (int i = 0; i < 8; ++i){ ss[i] = __shfl(s_j, k + i); ww[i] = __shfl(w_j, k + i); }
      #pragma unroll
      for (int i = 0; i < 8; ++i){ hh[i] = h2[(size_t)ss[i] * 64 + lane]; }
      #pragma unroll
      for (int i = 0; i < 8; ++i){
        acc.x = fmaf(ww[i], hh[i].x, acc.x);
        acc.y = fmaf(ww[i], hh[i].y, acc.y);
      }
    }
    for (; k < rem; ++k){
      int s = __shfl(s_j, k); float w = __shfl(w_j, k);
      float2 hh = h2[(size_t)s * 64 + lane];
      acc.x = fmaf(w, hh.x, acc.x);
      acc.y = fmaf(w, hh.y, acc.y);
    }
  }
  float inv = 1.f / den;
  float2 bv = ((const float2*)bias)[lane];
  float2 o2;
  o2.x = fmaxf(acc.x * inv + bv.x, 0.f);
  o2.y = fmaxf(acc.y * inv + bv.y, 0.f);
  osh[wave * 64 + lane] = o2;
  __syncthreads();
  float2 p;
  if (wave < 2){
    float2 a = osh[2 * wave * 64 + lane], b = osh[(2 * wave + 1) * 64 + lane];
    p.x = fmaxf(a.x, b.x); p.y = fmaxf(a.y, b.y);
    ((float2*)xout)[(size_t)(group * 2 + wave) * 64 + lane] = p;
  }
  __syncthreads();
  if (wave < 2) osh[wave * 64 + lane] = p;   // pooled rows 0,1
  __syncthreads();
  float* part = partials + ((group & 63) << 8);
  if (wave == 0){
    float2 a = osh[lane], b = osh[64 + lane];
    atomicAdd(&part[2 * lane],     a.x + b.x);
    atomicAdd(&part[2 * lane + 1], a.y + b.y);
  } else if (wave == 1){
    float2 a = osh[lane], b = osh[64 + lane];
    atomicAdd(&part[128 + 2 * lane],     a.x * a.x + b.x * b.x);
    atomicAdd(&part[128 + 2 * lane + 1], a.y * a.y + b.y * b.y);
  }
}

// ---------------- mega1: CSR L1+L2 CO-DISPATCHED with layer-1 GEMM ----------------------
// blocks 0..31: L1 CSR (no dedupe) + zero BN partials. blocks 32..63: L2 CSR (pair-dedupe
// bitmap) + write keep-mask mask2[e] to global (so the L3 build in the NEXT launch can
// skip re-doing the L2 dedupe — removes the old role-2, mega1's longest pole).
// blocks 64..1087: layer-1 GEMM (1024 tiles of 32 rows) + es/ed epilogue.
__global__ __launch_bounds__(256, 2)
void mega1(const float* __restrict__ x0, const float* __restrict__ W0,
           const float* __restrict__ a_s, const float* __restrict__ a_d,
           const int* __restrict__ src0, const int* __restrict__ dst0,
           float* __restrict__ C, float* __restrict__ es, float* __restrict__ ed,
           int* __restrict__ csr1, int* __restrict__ csr2,
           int* __restrict__ rs1, int* __restrict__ rs2,
           int* __restrict__ cnt1, int* __restrict__ cnt2,
           unsigned char* __restrict__ mask2, float* __restrict__ partials_all){
  __shared__ __align__(16) char smem[45056];   // union: csr 36KB / gemm 41KB
  __shared__ int wsum[4];
  int t = threadIdx.x;
  int raw = blockIdx.x;

  if (raw < 64){
    int* bm2 = (int*)smem;          // [8192] 32 KB
    int* h   = bm2 + 8192;          // [1024]  4 KB
    int g = raw & 31, ebase = g * EPG;

    if (raw < 32){
      // ---- L1: no dedupe, 1024 bins; also zero the 3 layers' BN partials ----
      for (int i = g * 256 + t; i < 3 * 64 * 256; i += 8192) partials_all[i] = 0.f;
      for (int i = t; i < 1024; i += 256) h[i] = 0;
      __syncthreads();
      for (int i = 0; i < 32; ++i){
        int e = ebase + i * 256 + t;
        int sv = src0[e], dv = dst0[e];
        if (sv != dv) atomicAdd(&h[dv & 1023], 1);
      }
      __syncthreads();
      scan_bins<4>(h, cnt1, rs1, 1024, g, ebase, wsum);
      for (int i = 0; i < 32; ++i){
        int e = ebase + i * 256 + t;
        int sv = src0[e], dv = dst0[e];
        if (sv != dv){
          int p = atomicAdd(&h[dv & 1023], 1);
          csr1[ebase + p] = sv;
        }
      }
    } else {
      // ---- L2: pair-dedupe (512x512 bitmap), 512 bins; publish mask2 ----
      for (int i = t; i < 8192; i += 256) bm2[i] = 0;
      for (int i = t; i < 512; i += 256) h[i] = 0;
      __syncthreads();
      unsigned int k2m = 0;
      for (int i = 0; i < 32; ++i){
        int e = ebase + i * 256 + t;
        int sv = src0[e], dv = dst0[e];
        unsigned char m2 = 0;
        if (sv != dv){
          int s2 = (sv >> 1) & 511, d2 = (dv >> 1) & 511;
          if (s2 != d2){
            int key = (s2 << 9) | d2;
            unsigned int bit = 1u << (key & 31);
            unsigned int old = atomicOr((unsigned int*)&bm2[key >> 5], bit);
            if (!(old & bit)){ k2m |= 1u << i; atomicAdd(&h[d2], 1); m2 = 1; }
          }
        }
        mask2[e] = m2;
      }
      __syncthreads();
      scan_bins<2>(h, cnt2, rs2, 512, g, ebase, wsum);
      for (int i = 0; i < 32; ++i){
        if ((k2m >> i) & 1u){
          int e = ebase + i * 256 + t;
          int sv = src0[e], dv = dst0[e];
          int p = atomicAdd(&h[(dv >> 1) & 511], 1);
          csr2[ebase + p] = sv >> 1;
        }
      }
    }
    return;
  }

  // ---- layer-1 GEMM tile (K=64, no BN) ----
  float* Ws   = (float*)smem;       // [64*128] 32 KB
  float* As_t = Ws + 8192;          // [64*36]   9 KB
  int tile = xcd_swz(raw - 64, 1024);
  int row0 = tile * 32;
  int c2 = t & 63, rg = t >> 6;
  float2 acc[8];
  #pragma unroll
  for (int i = 0; i < 8; ++i){ acc[i].x = 0.f; acc[i].y = 0.f; }

  for (int i = t; i < 8192; i += 256) Ws[i] = W0[i];
  #pragma unroll
  for (int it = 0; it < 8; ++it){
    int i = it * 256 + t;
    int r = i >> 6, kk = i & 63;
    As_t[kk * 36 + r] = x0[(size_t)(row0 + r) * 64 + kk];
  }
  __syncthreads();
  #pragma unroll 8
  for (int kk = 0; kk < 64; ++kk){
    float2 w = *(float2*)&Ws[kk * 128 + c2 * 2];
    float4 a0 = *(float4*)&As_t[kk * 36 + rg * 8];
    float4 a1 = *(float4*)&As_t[kk * 36 + rg * 8 + 4];
    acc[0].x = fmaf(a0.x, w.x, acc[0].x); acc[0].y = fmaf(a0.x, w.y, acc[0].y);
    acc[1].x = fmaf(a0.y, w.x, acc[1].x); acc[1].y = fmaf(a0.y, w.y, acc[1].y);
    acc[2].x = fmaf(a0.z, w.x, acc[2].x); acc[2].y = fmaf(a0.z, w.y, acc[2].y);
    acc[3].x = fmaf(a0.w, w.x, acc[3].x); acc[3].y = fmaf(a0.w, w.y, acc[3].y);
    acc[4].x = fmaf(a1.x, w.x, acc[4].x); acc[4].y = fmaf(a1.x, w.y, acc[4].y);
    acc[5].x = fmaf(a1.y, w.x, acc[5].x); acc[5].y = fmaf(a1.y, w.y, acc[5].y);
    acc[6].x = fmaf(a1.z, w.x, acc[6].x); acc[6].y = fmaf(a1.z, w.y, acc[6].y);
    acc[7].x = fmaf(a1.w, w.x, acc[7].x); acc[7].y = fmaf(a1.w, w.y, acc[7].y);
  }
  float2 as2 = ((const float2*)a_s)[c2];
  float2 ad2 = ((const float2*)a_d)[c2];
  float2* C2 = (float2*)C;
  #pragma unroll
  for (int i = 0; i < 8; ++i){
    int r = row0 + rg * 8 + i;
    C2[(size_t)r * 64 + c2] = acc[i];
    float e1 = acc[i].x * as2.x + acc[i].y * as2.y;
    float e2 = acc[i].x * ad2.x + acc[i].y * ad2.y;
    #pragma unroll
    for (int o = 32; o; o >>= 1){ e1 += __shfl_xor(e1, o); e2 += __shfl_xor(e2, o); }
    if (c2 == 0){ es[r] = e1; ed[r] = e2; }
  }
}

// ---------------- gat1h: layer-1 GAT CO-DISPATCHED with L3 CSR build --------------------
// blocks 0..31: L3 CSR from mask2 (no L2-dedupe redo: candidates are exactly the L2
// survivors; the surviving (s3,d3) SET is claim-order independent => csr3 content exact).
// blocks 32..8223: gat1 groups (4 nodes each), identical to r5's gat_pool.
__global__ __launch_bounds__(256, 2)
void gat1h(const float* __restrict__ h, const float* __restrict__ es,
           const float* __restrict__ ed, const int* __restrict__ src0,
           const int* __restrict__ dst0, const unsigned char* __restrict__ mask2,
           const int* __restrict__ csr1, const int* __restrict__ rs1,
           const int* __restrict__ cnt1,
           int* __restrict__ csr3, int* __restrict__ rs3, int* __restrict__ cnt3,
           const float* __restrict__ bias, float* __restrict__ xout,
           float* __restrict__ partials0){
  __shared__ __align__(16) int sm[2048 + 256];   // CSR: bm3+h (9KB) / gat: osh (2KB)
  __shared__ int wsum[4];
  int t = threadIdx.x;
  int raw = blockIdx.x;

  if (raw < 32){
    int* bm3 = sm;           // [2048] 8 KB
    int* h3  = bm3 + 2048;   // [256]  1 KB
    int g = raw, ebase = g * EPG;
    for (int i = t; i < 2048; i += 256) bm3[i] = 0;
    if (t < 256) h3[t] = 0;
    __syncthreads();
    unsigned int k3m = 0;
    for (int i = 0; i < 32; ++i){
      int e = ebase + i * 256 + t;
      if (mask2[e]){
        int sv = src0[e], dv = dst0[e];
        int s3 = (sv >> 2) & 255, d3 = (dv >> 2) & 255;
        if (s3 != d3){
          int key3 = (s3 << 8) | d3;
          unsigned int b3 = 1u << (key3 & 31);
          unsigned int o3 = atomicOr((unsigned int*)&bm3[key3 >> 5], b3);
          if (!(o3 & b3)){ k3m |= 1u << i; atomicAdd(&h3[d3], 1); }
        }
      }
    }
    __syncthreads();
    scan_bins<1>(h3, cnt3, rs3, 256, g, ebase, wsum);
    for (int i = 0; i < 32; ++i){
      if ((k3m >> i) & 1u){
        int e = ebase + i * 256 + t;
        int sv = src0[e], dv = dst0[e];
        int p = atomicAdd(&h3[(dv >> 2) & 255], 1);
        csr3[ebase + p] = sv >> 2;
      }
    }
    return;
  }

  int group = xcd_swz(raw - 32, 8192);
  gat_group(h, es, ed, csr1, rs1, cnt1, bias, xout, partials0, group, (float2*)sm);
}

// ---------------- GEMM (K=128) + attention terms; BN stats from 64-bank partials --------
__global__ __launch_bounds__(256)
void gemm_attn128(const float* __restrict__ A, const float* __restrict__ W,
                  const float* __restrict__ partials, float invM,
                  const float* __restrict__ a_s, const float* __restrict__ a_d,
                  float* __restrict__ C, float* __restrict__ es, float* __restrict__ ed){
  __shared__ float Ws[64 * 128];    // 32 KB
  __shared__ float As_t[64 * 36];   // 9 KB
  __shared__ float red[256];
  __shared__ float bnmu[128], bnrs[128];
  int t = threadIdx.x;
  {
    float s = 0.f;
    #pragma unroll
    for (int k = 0; k < 64; ++k) s += partials[(k << 8) + t];
    red[t] = s;
  }
  __syncthreads();
  if (t < 128){
    float mu = red[t] * invM;
    float var = red[128 + t] * invM - mu * mu;
    bnmu[t] = mu; bnrs[t] = rsqrtf(var + EPS_BN);
  }
  int bid = xcd_swz(blockIdx.x, gridDim.x);
  int row0 = bid * 32;
  int c2 = t & 63, rg = t >> 6;
  float2 acc[8];
  #pragma unroll
  for (int i = 0; i < 8; ++i){ acc[i].x = 0.f; acc[i].y = 0.f; }

  for (int k0 = 0; k0 < 128; k0 += 64){
    __syncthreads();
    for (int i = t; i < 64 * 128; i += 256)
      Ws[i] = W[(size_t)(k0 + (i >> 7)) * 128 + (i & 127)];
    #pragma unroll
    for (int it = 0; it < 8; ++it){
      int i = it * 256 + t;
      int r = i >> 6, kk = i & 63;
      float v = A[(size_t)(row0 + r) * 128 + k0 + kk];
      v = (v - bnmu[k0 + kk]) * bnrs[k0 + kk];
      As_t[kk * 36 + r] = v;
    }
    __syncthreads();
    #pragma unroll 8
    for (int kk = 0; kk < 64; ++kk){
      float2 w = *(float2*)&Ws[kk * 128 + c2 * 2];
      float4 a0 = *(float4*)&As_t[kk * 36 + rg * 8];
      float4 a1 = *(float4*)&As_t[kk * 36 + rg * 8 + 4];
      acc[0].x = fmaf(a0.x, w.x, acc[0].x); acc[0].y = fmaf(a0.x, w.y, acc[0].y);
      acc[1].x = fmaf(a0.y, w.x, acc[1].x); acc[1].y = fmaf(a0.y, w.y, acc[1].y);
      acc[2].x = fmaf(a0.z, w.x, acc[2].x); acc[2].y = fmaf(a0.z, w.y, acc[2].y);
      acc[3].x = fmaf(a0.w, w.x, acc[3].x); acc[3].y = fmaf(a0.w, w.y, acc[3].y);
      acc[4].x = fmaf(a1.x, w.x, acc[4].x); acc[4].y = fmaf(a1.x, w.y, acc[4].y);
      acc[5].x = fmaf(a1.y, w.x, acc[5].x); acc[5].y = fmaf(a1.y, w.y, acc[5].y);
      acc[6].x = fmaf(a1.z, w.x, acc[6].x); acc[6].y = fmaf(a1.z, w.y, acc[6].y);
      acc[7].x = fmaf(a1.w, w.x, acc[7].x); acc[7].y = fmaf(a1.w, w.y, acc[7].y);
    }
  }
  float2 as2 = ((const float2*)a_s)[c2];
  float2 ad2 = ((const float2*)a_d)[c2];
  float2* C2 = (float2*)C;
  #pragma unroll
  for (int i = 0; i < 8; ++i){
    int r = row0 + rg * 8 + i;
    C2[(size_t)r * 64 + c2] = acc[i];
    float e1 = acc[i].x * as2.x + acc[i].y * as2.y;
    float e2 = acc[i].x * ad2.x + acc[i].y * ad2.y;
    #pragma unroll
    for (int o = 32; o; o >>= 1){ e1 += __shfl_xor(e1, o); e2 += __shfl_xor(e2, o); }
    if (c2 == 0){ es[r] = e1; ed[r] = e2; }
  }
}

// ---------------- gat_pool (layers 2/3): 4 nodes per block, r5 form ----------------------
__global__ void gat_pool(const float* __restrict__ h, const float* __restrict__ es,
                         const float* __restrict__ ed, const int* __restrict__ csr_src,
                         const int* __restrict__ row_start, const int* __restrict__ row_cnt,
                         const float* __restrict__ bias, float* __restrict__ xout,
                         float* __restrict__ partials, int M){
  __shared__ float2 osh[4 * 64];
  int bid = xcd_swz(blockIdx.x, gridDim.x);
  gat_group(h, es, ed, csr_src, row_start, row_cnt, bias, xout, partials, bid, osh);
}

// ---------------- final BatchNorm: reduce partials + normalize, one kernel ---------------
__global__ __launch_bounds__(256)
void bn_norm(const float* __restrict__ in, const float* __restrict__ partials,
             float* __restrict__ out, int M){
  __shared__ float red[256];
  __shared__ float mu_s[128], rs_s[128];
  int t = threadIdx.x;
  {
    float s = 0.f;
    #pragma unroll
    for (int k = 0; k < 64; ++k) s += partials[(k << 8) + t];
    red[t] = s;
  }
  __syncthreads();
  if (t < 128){
    float mu = red[t] / (float)M;
    float var = red[128 + t] / (float)M - mu * mu;
    mu_s[t] = mu; rs_s[t] = rsqrtf(var + EPS_BN);
  }
  __syncthreads();
  int total = M * 128;
  for (int idx = blockIdx.x * 256 + t; idx < total; idx += gridDim.x * 256){
    int c = idx & 127;
    out[idx] = (in[idx] - mu_s[c]) * rs_s[c];
  }
}

extern "C" void kernel_launch(void* const* d_in, const int* in_sizes, int n_in,
                              void* d_out, int out_size, void* d_ws, size_t ws_size,
                              hipStream_t stream){
  const float* x0   = (const float*)d_in[0];
  const float* W0   = (const float*)d_in[1];
  const float* W1   = (const float*)d_in[2];
  const float* W2   = (const float*)d_in[3];
  const float* attS = (const float*)d_in[4];
  const float* attD = (const float*)d_in[5];
  const float* bias = (const float*)d_in[6];
  const int*   src0 = (const int*)d_in[7];
  const int*   dst0 = src0 + E_TOTAL;
  float* out = (float*)d_out;                  // (32, 16384) f32

  char* ws = (char*)d_ws;
  float*         Hbuf   = (float*)(ws);                        // 16 MB
  float*         Xbuf   = (float*)(ws + 16 * MB);              //  8 MB (pooled)
  int*           csr1   = (int*)  (ws + 24 * MB);              //  1 MB
  int*           csr2   = (int*)  (ws + 25 * MB);              //  1 MB
  int*           csr3   = (int*)  (ws + 26 * MB);              //  1 MB
  float*         es     = (float*)(ws + 27 * MB);              // 128 KB
  float*         ed     = (float*)(ws + 27 * MB + 128 * KB);   // 128 KB
  int*           rs1    = (int*)  (ws + 27 * MB + 256 * KB);   // 128 KB
  int*           rs2    = (int*)  (ws + 27 * MB + 384 * KB);   //  64 KB
  int*           rs3    = (int*)  (ws + 27 * MB + 448 * KB);   //  32 KB
  int*           cnt1   = (int*)  (ws + 27 * MB + 480 * KB);   // 128 KB
  int*           cnt2   = (int*)  (ws + 27 * MB + 608 * KB);   //  64 KB
  int*           cnt3   = (int*)  (ws + 27 * MB + 672 * KB);   //  32 KB
  float*         parts  = (float*)(ws + 27 * MB + 704 * KB);   // 192 KB (3 x 64 x 256 f)
  unsigned char* mask2  = (unsigned char*)(ws + 27 * MB + 896 * KB); // 256 KB
  float* parts0 = parts, *parts1 = parts + 64 * 256, *parts2 = parts + 2 * 64 * 256;

  // ---- CSR L1+L2 co-dispatched with layer-1 GEMM; publishes mask2; zeroes partials ----
  mega1<<<1088, 256, 0, stream>>>(x0, W0, attS, attD, src0, dst0, Hbuf, es, ed,
                                  csr1, csr2, rs1, rs2, cnt1, cnt2, mask2, parts);

  // ---- layer 1 aggregate co-dispatched with L3 CSR build (blocks 0..31) ----
  gat1h<<<8224, 256, 0, stream>>>(Hbuf, es, ed, src0, dst0, mask2,
                                  csr1, rs1, cnt1, csr3, rs3, cnt3,
                                  bias, Xbuf, parts0);

  // ---- layer 2 ----
  gemm_attn128<<<512, 256, 0, stream>>>(Xbuf, W1, parts0, 1.f / 16384.f,
                                        attS + 128, attD + 128, Hbuf, es, ed);
  gat_pool<<<4096, 256, 0, stream>>>(Hbuf, es, ed, csr2, rs2, cnt2, bias + 128, Xbuf,
                                     parts1, 16384);

  // ---- layer 3 ----
  gemm_attn128<<<256, 256, 0, stream>>>(Xbuf, W2, parts1, 1.f / 8192.f,
                                        attS + 256, attD + 256, Hbuf, es, ed);
  gat_pool<<<2048, 256, 0, stream>>>(Hbuf, es, ed, csr3, rs3, cnt3, bias + 256, Xbuf,
                                     parts2, 8192);

  // ---- final BN: reduce partials + normalize ----
  bn_norm<<<512, 256, 0, stream>>>(Xbuf, parts2, out, 4096);
}

// Round 9
// 205.218 us; speedup vs baseline: 4.2112x; 1.0125x over previous
//
#include <hip/hip_runtime.h>

// Problem constants: B=32 graphs, N=1024 nodes/graph, F=64, D=128, DEG=8
#define E_TOTAL 262144     // B*N*DEG
#define NGRAPH  32
#define EPG     8192       // edges per graph
#define EPS_BN  1e-5f
#define MB (1u << 20)
#define KB (1u << 10)

// SESSION LESSONS (measured):
//  - r3/r6: in-kernel cross-block sync costs 45-500 us on MI355X (agent-scope
//    release/acquire => per-XCD L2 writeback/invalidate storms). Launch boundaries
//    (~9.5 us, fitted slope across r0-r5) are the cheapest device-wide sync.
//  - r7: gat wants max independent waves; batching rows/block couples variable-degree
//    rows via __syncthreads and regresses.
//  - r8: moving the L2-dedupe redo off mega1 via a global mask is neutral (the CSR
//    tail was already hidden behind the 1024 GEMM tiles).
//  - Structure floor: 7 dispatches (3 BN global syncs + 3 gemm->gat syncs are true
//    data dependencies); kernel work ~50-60 us; rest is boundary + harness fills.

__device__ __forceinline__ float lrelu(float x){ return x > 0.f ? x : 0.2f * x; }

// XCD-aware block swizzle (locality-neutral measured, harmless).
__device__ __forceinline__ int xcd_swz(int b, int n){ return (b & 7) * (n >> 3) + (b >> 3); }

// exclusive scan of B = 256*Q LDS bins by 256 threads; writes cnt/row_start globals,
// leaves per-bin exclusive cursors in h. Caller must barrier before entry.
template<int Q>
__device__ __forceinline__ void scan_bins(int* h, int* cnt_g, int* rs_g, int B, int g,
                                          int ebase, int* wsum){
  int t = threadIdx.x, lane = t & 63, w = t >> 6;
  int c[Q]; int s = 0;
  #pragma unroll
  for (int i = 0; i < Q; ++i){ c[i] = h[t * Q + i]; s += c[i]; }
  int v = s;
  #pragma unroll
  for (int o = 1; o < 64; o <<= 1){ int u = __shfl_up(v, o); if (lane >= o) v += u; }
  if (lane == 63) wsum[w] = v;
  __syncthreads();
  if (t == 0){ int run = 0;
    #pragma unroll
    for (int i = 0; i < 4; ++i){ int x = wsum[i]; wsum[i] = run; run += x; } }
  __syncthreads();
  int run = v - s + wsum[w];
  #pragma unroll
  for (int i = 0; i < Q; ++i){
    cnt_g[g * B + t * Q + i] = c[i];
    rs_g [g * B + t * Q + i] = ebase + run;
    h[t * Q + i] = run;
    run += c[i];
  }
  __syncthreads();
}

// ---------------- mega1: CSR build (all 3 layers) CO-DISPATCHED with layer-1 GEMM -------
// blocks 0..95: CSR. role 0 (0-31): L1 hist+scan+scatter (no dedupe) + zero the 3 layers'
// BN partial arrays. role 1: L2 pair-dedupe. role 2: L2-redo + L3 dedupe. 256 thr,
// 32 edges/thread. blocks 96..1119: layer-1 GEMM (1024 tiles of 32 rows) + es/ed.
__global__ __launch_bounds__(256, 2)
void mega1(const float* __restrict__ x0, const float* __restrict__ W0,
           const float* __restrict__ a_s, const float* __restrict__ a_d,
           const int* __restrict__ src0, const int* __restrict__ dst0,
           float* __restrict__ C, float* __restrict__ es, float* __restrict__ ed,
           int* __restrict__ csr1, int* __restrict__ csr2, int* __restrict__ csr3,
           int* __restrict__ rs1, int* __restrict__ rs2, int* __restrict__ rs3,
           int* __restrict__ cnt1, int* __restrict__ cnt2, int* __restrict__ cnt3,
           float* __restrict__ partials_all){
  __shared__ __align__(16) char smem[45072];   // union: csr 44KB / gemm 41KB
  __shared__ int wsum[4];
  int t = threadIdx.x;
  int raw = blockIdx.x;

  if (raw < 96){
    int* bm2 = (int*)smem;          // [8192] 32 KB
    int* bm3 = bm2 + 8192;          // [2048]  8 KB
    int* h   = bm3 + 2048;          // [1024]  4 KB
    int role = raw >> 5, g = raw & 31, ebase = g * EPG;

    if (role == 0){
      // zero 3 layers x 64 banks x 256 BN partials (49152 floats) across 32 blocks
      for (int i = g * 256 + t; i < 3 * 64 * 256; i += 8192) partials_all[i] = 0.f;
      // ---- L1: no dedupe, 1024 bins ----
      for (int i = t; i < 1024; i += 256) h[i] = 0;
      __syncthreads();
      for (int i = 0; i < 32; ++i){
        int e = ebase + i * 256 + t;
        int sv = src0[e], dv = dst0[e];
        if (sv != dv) atomicAdd(&h[dv & 1023], 1);
      }
      __syncthreads();
      scan_bins<4>(h, cnt1, rs1, 1024, g, ebase, wsum);
      for (int i = 0; i < 32; ++i){
        int e = ebase + i * 256 + t;
        int sv = src0[e], dv = dst0[e];
        if (sv != dv){
          int p = atomicAdd(&h[dv & 1023], 1);
          csr1[ebase + p] = sv;
        }
      }
    } else if (role == 1){
      // ---- L2: pair-dedupe (512x512 bitmap), 512 bins ----
      for (int i = t; i < 8192; i += 256) bm2[i] = 0;
      for (int i = t; i < 512; i += 256) h[i] = 0;
      __syncthreads();
      unsigned int k2m = 0;
      for (int i = 0; i < 32; ++i){
        int e = ebase + i * 256 + t;
        int sv = src0[e], dv = dst0[e];
        if (sv != dv){
          int s2 = (sv >> 1) & 511, d2 = (dv >> 1) & 511;
          if (s2 != d2){
            int key = (s2 << 9) | d2;
            unsigned int bit = 1u << (key & 31);
            unsigned int old = atomicOr((unsigned int*)&bm2[key >> 5], bit);
            if (!(old & bit)){ k2m |= 1u << i; atomicAdd(&h[d2], 1); }
          }
        }
      }
      __syncthreads();
      scan_bins<2>(h, cnt2, rs2, 512, g, ebase, wsum);
      for (int i = 0; i < 32; ++i){
        if ((k2m >> i) & 1u){
          int e = ebase + i * 256 + t;
          int sv = src0[e], dv = dst0[e];
          int p = atomicAdd(&h[(dv >> 1) & 511], 1);
          csr2[ebase + p] = sv >> 1;
        }
      }
    } else {
      // ---- L3: redo L2 dedupe (independent bitmap) then L3 dedupe, 256 bins ----
      for (int i = t; i < 8192; i += 256) bm2[i] = 0;
      for (int i = t; i < 2048; i += 256) bm3[i] = 0;
      for (int i = t; i < 256; i += 256) h[i] = 0;
      __syncthreads();
      unsigned int k3m = 0;
      for (int i = 0; i < 32; ++i){
        int e = ebase + i * 256 + t;
        int sv = src0[e], dv = dst0[e];
        if (sv != dv){
          int s2 = (sv >> 1) & 511, d2 = (dv >> 1) & 511;
          if (s2 != d2){
            int key = (s2 << 9) | d2;
            unsigned int bit = 1u << (key & 31);
            unsigned int old = atomicOr((unsigned int*)&bm2[key >> 5], bit);
            if (!(old & bit)){
              int s3 = (sv >> 2) & 255, d3 = (dv >> 2) & 255;
              if (s3 != d3){
                int key3 = (s3 << 8) | d3;
                unsigned int b3 = 1u << (key3 & 31);
                unsigned int o3 = atomicOr((unsigned int*)&bm3[key3 >> 5], b3);
                if (!(o3 & b3)){ k3m |= 1u << i; atomicAdd(&h[d3], 1); }
              }
            }
          }
        }
      }
      __syncthreads();
      scan_bins<1>(h, cnt3, rs3, 256, g, ebase, wsum);
      for (int i = 0; i < 32; ++i){
        if ((k3m >> i) & 1u){
          int e = ebase + i * 256 + t;
          int sv = src0[e], dv = dst0[e];
          int p = atomicAdd(&h[(dv >> 2) & 255], 1);
          csr3[ebase + p] = sv >> 2;
        }
      }
    }
    return;
  }

  // ---- layer-1 GEMM tile (K=64, no BN) ----
  float* Ws   = (float*)smem;       // [64*128] 32 KB
  float* As_t = Ws + 8192;          // [64*36]   9 KB
  int tile = xcd_swz(raw - 96, 1024);
  int row0 = tile * 32;
  int c2 = t & 63, rg = t >> 6;
  float2 acc[8];
  #pragma unroll
  for (int i = 0; i < 8; ++i){ acc[i].x = 0.f; acc[i].y = 0.f; }

  for (int i = t; i < 8192; i += 256) Ws[i] = W0[i];
  #pragma unroll
  for (int it = 0; it < 8; ++it){
    int i = it * 256 + t;
    int r = i >> 6, kk = i & 63;
    As_t[kk * 36 + r] = x0[(size_t)(row0 + r) * 64 + kk];
  }
  __syncthreads();
  #pragma unroll 8
  for (int kk = 0; kk < 64; ++kk){
    float2 w = *(float2*)&Ws[kk * 128 + c2 * 2];
    float4 a0 = *(float4*)&As_t[kk * 36 + rg * 8];
    float4 a1 = *(float4*)&As_t[kk * 36 + rg * 8 + 4];
    acc[0].x = fmaf(a0.x, w.x, acc[0].x); acc[0].y = fmaf(a0.x, w.y, acc[0].y);
    acc[1].x = fmaf(a0.y, w.x, acc[1].x); acc[1].y = fmaf(a0.y, w.y, acc[1].y);
    acc[2].x = fmaf(a0.z, w.x, acc[2].x); acc[2].y = fmaf(a0.z, w.y, acc[2].y);
    acc[3].x = fmaf(a0.w, w.x, acc[3].x); acc[3].y = fmaf(a0.w, w.y, acc[3].y);
    acc[4].x = fmaf(a1.x, w.x, acc[4].x); acc[4].y = fmaf(a1.x, w.y, acc[4].y);
    acc[5].x = fmaf(a1.y, w.x, acc[5].x); acc[5].y = fmaf(a1.y, w.y, acc[5].y);
    acc[6].x = fmaf(a1.z, w.x, acc[6].x); acc[6].y = fmaf(a1.z, w.y, acc[6].y);
    acc[7].x = fmaf(a1.w, w.x, acc[7].x); acc[7].y = fmaf(a1.w, w.y, acc[7].y);
  }
  float2 as2 = ((const float2*)a_s)[c2];
  float2 ad2 = ((const float2*)a_d)[c2];
  float2* C2 = (float2*)C;
  #pragma unroll
  for (int i = 0; i < 8; ++i){
    int r = row0 + rg * 8 + i;
    C2[(size_t)r * 64 + c2] = acc[i];
    float e1 = acc[i].x * as2.x + acc[i].y * as2.y;
    float e2 = acc[i].x * ad2.x + acc[i].y * ad2.y;
    #pragma unroll
    for (int o = 32; o; o >>= 1){ e1 += __shfl_xor(e1, o); e2 += __shfl_xor(e2, o); }
    if (c2 == 0){ es[r] = e1; ed[r] = e2; }
  }
}

// ---------------- GEMM (K=128) + attention terms; BN stats from 64-bank partials --------
// Prologue reduces partials[64][256] (written by the preceding gat_pool) into mu/rsig.
// The producer->consumer kernel-launch boundary is the only synchronization needed.
__global__ __launch_bounds__(256)
void gemm_attn128(const float* __restrict__ A, const float* __restrict__ W,
                  const float* __restrict__ partials, float invM,
                  const float* __restrict__ a_s, const float* __restrict__ a_d,
                  float* __restrict__ C, float* __restrict__ es, float* __restrict__ ed){
  __shared__ float Ws[64 * 128];    // 32 KB
  __shared__ float As_t[64 * 36];   // 9 KB
  __shared__ float red[256];
  __shared__ float bnmu[128], bnrs[128];
  int t = threadIdx.x;
  {
    float s = 0.f;
    #pragma unroll
    for (int k = 0; k < 64; ++k) s += partials[(k << 8) + t];
    red[t] = s;
  }
  __syncthreads();
  if (t < 128){
    float mu = red[t] * invM;
    float var = red[128 + t] * invM - mu * mu;
    bnmu[t] = mu; bnrs[t] = rsqrtf(var + EPS_BN);
  }
  int bid = xcd_swz(blockIdx.x, gridDim.x);
  int row0 = bid * 32;
  int c2 = t & 63, rg = t >> 6;
  float2 acc[8];
  #pragma unroll
  for (int i = 0; i < 8; ++i){ acc[i].x = 0.f; acc[i].y = 0.f; }

  for (int k0 = 0; k0 < 128; k0 += 64){
    __syncthreads();
    for (int i = t; i < 64 * 128; i += 256)
      Ws[i] = W[(size_t)(k0 + (i >> 7)) * 128 + (i & 127)];
    #pragma unroll
    for (int it = 0; it < 8; ++it){
      int i = it * 256 + t;
      int r = i >> 6, kk = i & 63;
      float v = A[(size_t)(row0 + r) * 128 + k0 + kk];
      v = (v - bnmu[k0 + kk]) * bnrs[k0 + kk];
      As_t[kk * 36 + r] = v;
    }
    __syncthreads();
    #pragma unroll 8
    for (int kk = 0; kk < 64; ++kk){
      float2 w = *(float2*)&Ws[kk * 128 + c2 * 2];
      float4 a0 = *(float4*)&As_t[kk * 36 + rg * 8];
      float4 a1 = *(float4*)&As_t[kk * 36 + rg * 8 + 4];
      acc[0].x = fmaf(a0.x, w.x, acc[0].x); acc[0].y = fmaf(a0.x, w.y, acc[0].y);
      acc[1].x = fmaf(a0.y, w.x, acc[1].x); acc[1].y = fmaf(a0.y, w.y, acc[1].y);
      acc[2].x = fmaf(a0.z, w.x, acc[2].x); acc[2].y = fmaf(a0.z, w.y, acc[2].y);
      acc[3].x = fmaf(a0.w, w.x, acc[3].x); acc[3].y = fmaf(a0.w, w.y, acc[3].y);
      acc[4].x = fmaf(a1.x, w.x, acc[4].x); acc[4].y = fmaf(a1.x, w.y, acc[4].y);
      acc[5].x = fmaf(a1.y, w.x, acc[5].x); acc[5].y = fmaf(a1.y, w.y, acc[5].y);
      acc[6].x = fmaf(a1.z, w.x, acc[6].x); acc[6].y = fmaf(a1.z, w.y, acc[6].y);
      acc[7].x = fmaf(a1.w, w.x, acc[7].x); acc[7].y = fmaf(a1.w, w.y, acc[7].y);
    }
  }
  float2 as2 = ((const float2*)a_s)[c2];
  float2 ad2 = ((const float2*)a_d)[c2];
  float2* C2 = (float2*)C;
  #pragma unroll
  for (int i = 0; i < 8; ++i){
    int r = row0 + rg * 8 + i;
    C2[(size_t)r * 64 + c2] = acc[i];
    float e1 = acc[i].x * as2.x + acc[i].y * as2.y;
    float e2 = acc[i].x * ad2.x + acc[i].y * ad2.y;
    #pragma unroll
    for (int o = 32; o; o >>= 1){ e1 += __shfl_xor(e1, o); e2 += __shfl_xor(e2, o); }
    if (c2 == 0){ es[r] = e1; ed[r] = e2; }
  }
}

// ---------------- GAT softmax-aggregate + bias + ReLU + pairwise max-pool ----------------
// one wave per dst node; block 256 -> nodes 4b..4b+3 = pool pairs; writes M/2 pooled rows.
// Epilogue also accumulates this block's 2 pooled rows into the layer's 64-bank BN
// partial array (sum + sumsq per channel) -> no separate bn_stats dispatch.
__global__ void gat_pool(const float* __restrict__ h, const float* __restrict__ es,
                         const float* __restrict__ ed, const int* __restrict__ csr_src,
                         const int* __restrict__ row_start, const int* __restrict__ row_cnt,
                         const float* __restrict__ bias, float* __restrict__ xout,
                         float* __restrict__ partials, int M){
  __shared__ float2 osh[4][64];
  int lane = threadIdx.x & 63;
  int wave = threadIdx.x >> 6;
  int bid = xcd_swz(blockIdx.x, gridDim.x);
  int n = bid * 4 + wave;
  int start = row_start[n];
  int cnt   = row_cnt[n];
  float edn = ed[n];
  float selfl = lrelu(es[n] + edn);

  float m_l = -1e30f, d_l = 0.f;
  int   s_c = 0; float l_c = 0.f;
  for (int c0 = 0; c0 < cnt; c0 += 64){
    int j = c0 + lane;
    if (j < cnt){
      int s = csr_src[start + j];
      float l = lrelu(es[s] + edn);
      if (c0 == 0){ s_c = s; l_c = l; }
      float mn = fmaxf(m_l, l);
      d_l = d_l * __expf(m_l - mn) + __expf(l - mn);
      m_l = mn;
    }
  }
  #pragma unroll
  for (int o = 32; o; o >>= 1){
    float m2 = __shfl_xor(m_l, o), d2 = __shfl_xor(d_l, o);
    float mn = fmaxf(m_l, m2);
    d_l = d_l * __expf(m_l - mn) + d2 * __expf(m2 - mn);
    m_l = mn;
  }
  float mf  = fmaxf(m_l, selfl);
  float den = d_l * __expf(m_l - mf) + __expf(selfl - mf);

  const float2* h2 = (const float2*)h;
  float sw = __expf(selfl - mf);
  float2 hv = h2[(size_t)n * 64 + lane];
  float2 acc; acc.x = sw * hv.x; acc.y = sw * hv.y;
  for (int c0 = 0; c0 < cnt; c0 += 64){
    int j = c0 + lane;
    int s_j; float w_j;
    if (c0 == 0){
      s_j = s_c;
      w_j = (lane < cnt) ? __expf(l_c - mf) : 0.f;
    } else {
      s_j = 0; w_j = 0.f;
      if (j < cnt){
        s_j = csr_src[start + j];
        w_j = __expf(lrelu(es[s_j] + edn) - mf);
      }
    }
    int rem = min(64, cnt - c0);
    int k = 0;
    for (; k + 8 <= rem; k += 8){
      int ss[8]; float ww[8]; float2 hh[8];
      #pragma unroll
      for (int i = 0; i < 8; ++i){ ss[i] = __shfl(s_j, k + i); ww[i] = __shfl(w_j, k + i); }
      #pragma unroll
      for (int i = 0; i < 8; ++i){ hh[i] = h2[(size_t)ss[i] * 64 + lane]; }
      #pragma unroll
      for (int i = 0; i < 8; ++i){
        acc.x = fmaf(ww[i], hh[i].x, acc.x);
        acc.y = fmaf(ww[i], hh[i].y, acc.y);
      }
    }
    for (; k < rem; ++k){
      int s = __shfl(s_j, k); float w = __shfl(w_j, k);
      float2 hh = h2[(size_t)s * 64 + lane];
      acc.x = fmaf(w, hh.x, acc.x);
      acc.y = fmaf(w, hh.y, acc.y);
    }
  }
  float inv = 1.f / den;
  float2 bv = ((const float2*)bias)[lane];
  float2 o2;
  o2.x = fmaxf(acc.x * inv + bv.x, 0.f);
  o2.y = fmaxf(acc.y * inv + bv.y, 0.f);
  osh[wave][lane] = o2;
  __syncthreads();
  float2 p;
  if (wave < 2){
    float2 a = osh[2 * wave][lane], b = osh[2 * wave + 1][lane];
    p.x = fmaxf(a.x, b.x); p.y = fmaxf(a.y, b.y);
    ((float2*)xout)[(size_t)(bid * 2 + wave) * 64 + lane] = p;
  }
  __syncthreads();
  if (wave < 2) osh[wave][lane] = p;   // pooled rows 0,1
  __syncthreads();
  float* part = partials + ((bid & 63) << 8);
  if (wave == 0){
    float2 a = osh[0][lane], b = osh[1][lane];
    atomicAdd(&part[2 * lane],     a.x + b.x);
    atomicAdd(&part[2 * lane + 1], a.y + b.y);
  } else if (wave == 1){
    float2 a = osh[0][lane], b = osh[1][lane];
    atomicAdd(&part[128 + 2 * lane],     a.x * a.x + b.x * b.x);
    atomicAdd(&part[128 + 2 * lane + 1], a.y * a.y + b.y * b.y);
  }
}

// ---------------- final BatchNorm: reduce partials + normalize, one kernel ---------------
__global__ __launch_bounds__(256)
void bn_norm(const float* __restrict__ in, const float* __restrict__ partials,
             float* __restrict__ out, int M){
  __shared__ float red[256];
  __shared__ float mu_s[128], rs_s[128];
  int t = threadIdx.x;
  {
    float s = 0.f;
    #pragma unroll
    for (int k = 0; k < 64; ++k) s += partials[(k << 8) + t];
    red[t] = s;
  }
  __syncthreads();
  if (t < 128){
    float mu = red[t] / (float)M;
    float var = red[128 + t] / (float)M - mu * mu;
    mu_s[t] = mu; rs_s[t] = rsqrtf(var + EPS_BN);
  }
  __syncthreads();
  int total = M * 128;
  for (int idx = blockIdx.x * 256 + t; idx < total; idx += gridDim.x * 256){
    int c = idx & 127;
    out[idx] = (in[idx] - mu_s[c]) * rs_s[c];
  }
}

extern "C" void kernel_launch(void* const* d_in, const int* in_sizes, int n_in,
                              void* d_out, int out_size, void* d_ws, size_t ws_size,
                              hipStream_t stream){
  const float* x0   = (const float*)d_in[0];
  const float* W0   = (const float*)d_in[1];
  const float* W1   = (const float*)d_in[2];
  const float* W2   = (const float*)d_in[3];
  const float* attS = (const float*)d_in[4];
  const float* attD = (const float*)d_in[5];
  const float* bias = (const float*)d_in[6];
  const int*   src0 = (const int*)d_in[7];
  const int*   dst0 = src0 + E_TOTAL;
  float* out = (float*)d_out;                  // (32, 16384) f32

  char* ws = (char*)d_ws;
  float* Hbuf   = (float*)(ws);                        // 16 MB
  float* Xbuf   = (float*)(ws + 16 * MB);              //  8 MB (pooled)
  int*   csr1   = (int*)  (ws + 24 * MB);              //  1 MB
  int*   csr2   = (int*)  (ws + 25 * MB);              //  1 MB
  int*   csr3   = (int*)  (ws + 26 * MB);              //  1 MB
  float* es     = (float*)(ws + 27 * MB);              // 128 KB
  float* ed     = (float*)(ws + 27 * MB + 128 * KB);   // 128 KB
  int*   rs1    = (int*)  (ws + 27 * MB + 256 * KB);   // 128 KB
  int*   rs2    = (int*)  (ws + 27 * MB + 384 * KB);   //  64 KB
  int*   rs3    = (int*)  (ws + 27 * MB + 448 * KB);   //  32 KB
  int*   cnt1   = (int*)  (ws + 27 * MB + 480 * KB);   // 128 KB
  int*   cnt2   = (int*)  (ws + 27 * MB + 608 * KB);   //  64 KB
  int*   cnt3   = (int*)  (ws + 27 * MB + 672 * KB);   //  32 KB
  float* parts  = (float*)(ws + 27 * MB + 704 * KB);   // 3 x 64 x 256 floats (192 KB)
  float* parts0 = parts, *parts1 = parts + 64 * 256, *parts2 = parts + 2 * 64 * 256;

  // ---- CSR (all 3 layers) co-dispatched with layer-1 GEMM; zeroes BN partials ----
  mega1<<<1120, 256, 0, stream>>>(x0, W0, attS, attD, src0, dst0, Hbuf, es, ed,
                                  csr1, csr2, csr3, rs1, rs2, rs3, cnt1, cnt2, cnt3,
                                  parts);

  // ---- layer 1 aggregate (+ BN partials for layer-2 stats) ----
  gat_pool<<<8192, 256, 0, stream>>>(Hbuf, es, ed, csr1, rs1, cnt1, bias, Xbuf,
                                     parts0, 32768);

  // ---- layer 2 ----
  gemm_attn128<<<512, 256, 0, stream>>>(Xbuf, W1, parts0, 1.f / 16384.f,
                                        attS + 128, attD + 128, Hbuf, es, ed);
  gat_pool<<<4096, 256, 0, stream>>>(Hbuf, es, ed, csr2, rs2, cnt2, bias + 128, Xbuf,
                                     parts1, 16384);

  // ---- layer 3 ----
  gemm_attn128<<<256, 256, 0, stream>>>(Xbuf, W2, parts1, 1.f / 8192.f,
                                        attS + 256, attD + 256, Hbuf, es, ed);
  gat_pool<<<2048, 256, 0, stream>>>(Hbuf, es, ed, csr3, rs3, cnt3, bias + 256, Xbuf,
                                     parts2, 8192);

  // ---- final BN: reduce partials + normalize ----
  bn_norm<<<512, 256, 0, stream>>>(Xbuf, parts2, out, 4096);
}